// Round 1
// baseline (1822.233 us; speedup 1.0000x reference)
//
#include <hip/hip_runtime.h>

typedef unsigned short u16;
typedef unsigned int   u32;

#define NN  400
#define EIN 3200
#define NE  3600
#define TT  2016

__device__ __forceinline__ float bf2f(u16 h){
  union{u32 u; float f;} v; v.u=((u32)h)<<16; return v.f;
}
__device__ __forceinline__ u16 f2bf(float f){
  union{float f; u32 u;} v; v.f=f;
  u32 r=v.u + 0x7FFFu + ((v.u>>16)&1u);
  return (u16)(r>>16);
}
__device__ __forceinline__ float lrelu(float x){ return x>0.f ? x : 0.2f*x; }

// per-dst edge softmax over CSR rows; alpha written normalized.
__device__ __forceinline__ void edge_softmax(int tid, const int* s_rp, const int* s_col,
                                             const float* s_als, const float* s_ald,
                                             float* s_alpha){
  if(tid<NN){
    int b=s_rp[tid], en=s_rp[tid+1];
    float ad=s_ald[tid];
    float mx=-1e30f;
    for(int j=b;j<en;j++){ float v=lrelu(s_als[s_col[j]]+ad); s_alpha[j]=v; mx=fmaxf(mx,v); }
    float den=0.f;
    for(int j=b;j<en;j++){ float ex=__expf(s_alpha[j]-mx); s_alpha[j]=ex; den+=ex; }
    float inv=1.f/den;
    for(int j=b;j<en;j++) s_alpha[j]*=inv;
  }
}

// ---------------- CSR build (deterministic, rank-by-edge-order) ----------------
__global__ __launch_bounds__(1024) void k_csr(const int* __restrict__ ei,
                                              int* __restrict__ row_ptr,
                                              int* __restrict__ col_src){
  __shared__ int s_dst[NE];
  __shared__ int s_deg[NN];
  __shared__ int s_rp[NN+1];
  int tid=threadIdx.x;
  for(int e=tid;e<NE;e+=1024)
    s_dst[e] = (e<EIN) ? ei[EIN+e] : (e-EIN);   // self loops appended
  __syncthreads();
  for(int d=tid;d<NN;d+=1024){
    int c=0;
    for(int j=0;j<NE;j++) c += (s_dst[j]==d);
    s_deg[d]=c;
  }
  __syncthreads();
  for(int d=tid;d<=NN;d+=1024){
    int acc=0;
    for(int j=0;j<d;j++) acc+=s_deg[j];
    s_rp[d]=acc;
    row_ptr[d]=acc;
  }
  __syncthreads();
  for(int e=tid;e<NE;e+=1024){
    int dd=s_dst[e];
    int rank=0;
    for(int j=0;j<e;j++) rank += (s_dst[j]==dd);
    int sv = (e<EIN) ? ei[e] : (e-EIN);
    col_src[s_rp[dd]+rank]=sv;
  }
}

// ---------------- weight folds ----------------
__global__ __launch_bounds__(256) void k_wpe(
    const float* __restrict__ Wp2, const float* __restrict__ bp2,
    const float* __restrict__ Wt1,
    const float* __restrict__ at1_src, const float* __restrict__ at1_dst,
    const float* __restrict__ Wt2, const float* __restrict__ at2_src, const float* __restrict__ at2_dst,
    float* __restrict__ W_pe, float* __restrict__ b_pe,
    float* __restrict__ wpe_s, float* __restrict__ wpe_d,
    float* __restrict__ wt1_as, float* __restrict__ wt1_ad,
    float* __restrict__ w2s, float* __restrict__ w2d)
{
  int tid=threadIdx.x;
  for(int i=tid;i<32*256;i+=256){
    int k=i>>8, j=i&255;
    float a=0.f;
    for(int m=0;m<32;m++) a+=Wp2[k*32+m]*Wt1[(64+m)*256+j];
    W_pe[i]=a;
  }
  { int j=tid;
    float a=0.f;
    for(int m=0;m<32;m++) a+=bp2[m]*Wt1[(64+m)*256+j];
    b_pe[j]=a; }
  __syncthreads();
  if(tid<128){
    int k=tid>>2, h=tid&3;
    float s=0.f,d=0.f;
    for(int cc=0;cc<64;cc++){ float wv=W_pe[k*256+h*64+cc]; s+=wv*at1_src[h*64+cc]; d+=wv*at1_dst[h*64+cc]; }
    wpe_s[tid]=s; wpe_d[tid]=d;
  }
  if(tid<128){
    int k=tid>>2, h=tid&3;
    float s=0.f,d=0.f;
    for(int cc=0;cc<64;cc++){ float wv=Wt1[k*256+h*64+cc]; s+=wv*at1_src[h*64+cc]; d+=wv*at1_dst[h*64+cc]; }
    wt1_as[tid]=s; wt1_ad[tid]=d;
  }
  if(tid>=128 && tid<192){
    int k=tid-128;
    float s=0.f,d=0.f;
    for(int cc=0;cc<64;cc++){ float wv=Wt2[k*64+cc]; s+=wv*at2_src[cc]; d+=wv*at2_dst[cc]; }
    w2s[k]=s; w2d[k]=d;
  }
}

// ---------------- static 2-layer GAT (single block) ----------------
__global__ __launch_bounds__(512) void k_static(
    const float* __restrict__ x_static,
    const float* __restrict__ Ws1, const float* __restrict__ as1_src, const float* __restrict__ as1_dst, const float* __restrict__ bs1,
    const float* __restrict__ Ws2, const float* __restrict__ as2_src, const float* __restrict__ as2_dst, const float* __restrict__ bs2,
    const int* __restrict__ row_ptr, const int* __restrict__ col_src,
    float* __restrict__ xs)
{
  __shared__ float s_x[NN][32];
  __shared__ float s_h[NN][33];
  __shared__ float s_als[NN], s_ald[NN];
  __shared__ float s_alpha[NE];
  __shared__ int   s_col[NE];
  __shared__ int   s_rp[NN+1];
  int tid=threadIdx.x;
  for(int i=tid;i<NE;i+=512) s_col[i]=col_src[i];
  if(tid<NN+1) s_rp[tid]=row_ptr[tid];
  for(int i=tid;i<NN*16;i+=512) s_x[i>>4][i&15]=x_static[i];
  __syncthreads();
  float r[32];
  #pragma unroll
  for(int cc=0;cc<32;cc++) r[cc]=0.f;
  // layer 1: 4 heads, Fin=16
  for(int h=0;h<4;h++){
    for(int i=tid;i<NN*32;i+=512){
      int n=i>>5, cc=i&31;
      float a=0.f;
      #pragma unroll
      for(int k=0;k<16;k++) a+=s_x[n][k]*Ws1[k*128+h*32+cc];
      s_h[n][cc]=a;
    }
    __syncthreads();
    if(tid<NN){
      float sa=0.f,da=0.f;
      #pragma unroll
      for(int cc=0;cc<32;cc++){ float hv=s_h[tid][cc]; sa+=hv*as1_src[h*32+cc]; da+=hv*as1_dst[h*32+cc]; }
      s_als[tid]=sa; s_ald[tid]=da;
    }
    __syncthreads();
    edge_softmax(tid,s_rp,s_col,s_als,s_ald,s_alpha);
    __syncthreads();
    if(tid<NN){
      int b=s_rp[tid], en=s_rp[tid+1];
      for(int j=b;j<en;j++){
        float a=s_alpha[j]; int s=s_col[j];
        #pragma unroll
        for(int cc=0;cc<32;cc++) r[cc]+=a*s_h[s][cc];
      }
    }
    __syncthreads();
  }
  if(tid<NN){
    #pragma unroll
    for(int cc=0;cc<32;cc++) s_x[tid][cc]=fmaxf(0.25f*r[cc]+bs1[cc],0.f);
  }
  __syncthreads();
  // layer 2: 1 head, Fin=32
  #pragma unroll
  for(int cc=0;cc<32;cc++) r[cc]=0.f;
  for(int i=tid;i<NN*32;i+=512){
    int n=i>>5, cc=i&31;
    float a=0.f;
    #pragma unroll
    for(int k=0;k<32;k++) a+=s_x[n][k]*Ws2[k*32+cc];
    s_h[n][cc]=a;
  }
  __syncthreads();
  if(tid<NN){
    float sa=0.f,da=0.f;
    #pragma unroll
    for(int cc=0;cc<32;cc++){ float hv=s_h[tid][cc]; sa+=hv*as2_src[cc]; da+=hv*as2_dst[cc]; }
    s_als[tid]=sa; s_ald[tid]=da;
  }
  __syncthreads();
  edge_softmax(tid,s_rp,s_col,s_als,s_ald,s_alpha);
  __syncthreads();
  if(tid<NN){
    int b=s_rp[tid], en=s_rp[tid+1];
    for(int j=b;j<en;j++){
      float a=s_alpha[j]; int s=s_col[j];
      #pragma unroll
      for(int cc=0;cc<32;cc++) r[cc]+=a*s_h[s][cc];
    }
    #pragma unroll
    for(int cc=0;cc<32;cc++) xs[tid*32+cc]=fmaxf(r[cc]+bs2[cc],0.f);
  }
}

// ---------------- calendar path: Bpre[t,256], Bal_{s,d}[t,4] ----------------
__global__ __launch_bounds__(256) void k_cal(
    const float* __restrict__ wd_emb, const float* __restrict__ sl_emb,
    const float* __restrict__ Wc1, const float* __restrict__ bc1,
    const float* __restrict__ Wc2, const float* __restrict__ bc2,
    const float* __restrict__ Wt1,
    const float* __restrict__ at1_src, const float* __restrict__ at1_dst,
    const float* __restrict__ b_pe,
    float* __restrict__ Bpre, float* __restrict__ Bal_s, float* __restrict__ Bal_d)
{
  const double PI=3.14159265358979323846;
  int t=blockIdx.x; int wd=t/288, sl=t%288; int tid=threadIdx.x;
  __shared__ float feat[32];
  __shared__ float c1[32];
  __shared__ float calv[32];
  __shared__ float bpre[256];
  if(tid<8) feat[tid]=wd_emb[wd*8+tid];
  if(tid>=8 && tid<24) feat[tid]=sl_emb[sl*16+(tid-8)];
  if(tid==24||tid==25){ float ta=(float)(2.0*PI/288.0)*(float)sl; feat[tid]=(tid==24)?sinf(ta):cosf(ta); }
  if(tid==26||tid==27){ float wa=(float)(2.0*PI/7.0)*(float)wd;   feat[tid]=(tid==26)?sinf(wa):cosf(wa); }
  if(tid==28) feat[28]=(wd>=5)?1.f:0.f;
  __syncthreads();
  if(tid<32){ float a=bc1[tid]; for(int k=0;k<29;k++) a+=feat[k]*Wc1[k*32+tid]; c1[tid]=fmaxf(a,0.f); }
  __syncthreads();
  if(tid<32){ float a=bc2[tid]; for(int k=0;k<32;k++) a+=c1[k]*Wc2[k*32+tid]; calv[tid]=a; }
  __syncthreads();
  { int j=tid; float a=b_pe[j];
    for(int k=0;k<32;k++) a+=calv[k]*Wt1[(32+k)*256+j];
    bpre[j]=a; Bpre[(size_t)t*256+j]=a; }
  __syncthreads();
  if(tid<8){ int hh=tid&3; const float* av=(tid<4)?at1_src:at1_dst;
    float a=0.f;
    for(int cc=0;cc<64;cc++) a+=bpre[hh*64+cc]*av[hh*64+cc];
    if(tid<4) Bal_s[t*4+hh]=a; else Bal_d[t*4+hh]=a; }
}

// ---------------- Apre[n,256], Aal_{s,d}[n,4] ----------------
__global__ __launch_bounds__(256) void k_apre(
    const float* __restrict__ xs, const float* __restrict__ Wt1,
    const float* __restrict__ wt1_as, const float* __restrict__ wt1_ad,
    float* __restrict__ Apre, float* __restrict__ Aal_s, float* __restrict__ Aal_d)
{
  int n=blockIdx.x, tid=threadIdx.x;
  __shared__ float sx[32];
  if(tid<32) sx[tid]=xs[n*32+tid];
  __syncthreads();
  float a=0.f;
  for(int k=0;k<32;k++) a+=sx[k]*Wt1[k*256+tid];
  Apre[(size_t)n*256+tid]=a;
  if(tid<8){ int hh=tid&3; const float* wv=(tid<4)?wt1_as:wt1_ad;
    float s=0.f;
    for(int k=0;k<32;k++) s+=sx[k]*wv[k*4+hh];
    if(tid<4) Aal_s[n*4+hh]=s; else Aal_d[n*4+hh]=s; }
}

// ---------------- fused temporal: GAT(4h) -> GAT(1h) -> head MLP, one block per t ----------------
__global__ __launch_bounds__(512) void k_temporal(
    const float* __restrict__ pf, const float* __restrict__ Wp1, const float* __restrict__ bp1,
    const float* __restrict__ Apre, const float* __restrict__ Aal_s, const float* __restrict__ Aal_d,
    const float* __restrict__ Bpre, const float* __restrict__ Bal_s, const float* __restrict__ Bal_d,
    const float* __restrict__ W_pe, const float* __restrict__ wpe_s, const float* __restrict__ wpe_d,
    const float* __restrict__ bt1,
    const float* __restrict__ Wt2, const float* __restrict__ w2s, const float* __restrict__ w2d,
    const float* __restrict__ bt2,
    const float* __restrict__ Wh1, const float* __restrict__ bh1,
    const float* __restrict__ Wh2, const float* __restrict__ bh2,
    const int* __restrict__ row_ptr, const int* __restrict__ col_src,
    float* __restrict__ Hout, float* __restrict__ pred)
{
  // LDS carve (139204 B): regions aliased across phases.
  __shared__ __align__(16) char smem[139204];
  float (*sP1)[33] = (float(*)[33])smem;           // [400][33] f32; later aliased as s_g
  u16   (*s_g)[66] = (u16(*)[66])smem;             // g1 / H bf16 [400][66]
  u16   (*s_h)[66] = (u16(*)[66])(smem+52800);     // h1/h2 bf16; later pj f32 [400][33]
  float* pjp       = (float*)(smem+52800);
  float* s_als     = (float*)(smem+105600);
  float* s_ald     = (float*)(smem+107200);
  float* s_alpha   = (float*)(smem+108800);
  int*   s_col     = (int*)(smem+123200);
  int*   s_rp      = (int*)(smem+137600);

  const int t=blockIdx.x, tid=threadIdx.x;
  for(int i=tid;i<NE;i+=512) s_col[i]=col_src[i];
  if(tid<NN+1) s_rp[tid]=row_ptr[tid];

  // P1[n,32] = relu(pf[n,t]@Wp1 + bp1), f32 in LDS
  if(tid<NN){
    const float* p = pf + ((size_t)tid*TT + t)*8;
    float x0=p[0],x1=p[1],x2=p[2],x3=p[3],x4=p[4],x5=p[5],x6=p[6],x7=p[7];
    #pragma unroll
    for(int k=0;k<32;k++){
      float a=bp1[k];
      a+=x0*Wp1[k];     a+=x1*Wp1[32+k];  a+=x2*Wp1[64+k];  a+=x3*Wp1[96+k];
      a+=x4*Wp1[128+k]; a+=x5*Wp1[160+k]; a+=x6*Wp1[192+k]; a+=x7*Wp1[224+k];
      sP1[tid][k]=fmaxf(a,0.f);
    }
  }
  float r[64];
  #pragma unroll
  for(int cc=0;cc<64;cc++) r[cc]=0.f;
  const int c  = tid&63;
  const int n0 = tid>>6;
  __syncthreads();

  // ======== temporal GAT layer 1 (4 heads) ========
  for(int h=0;h<4;h++){
    {
      float wcol[32];
      #pragma unroll
      for(int k=0;k<32;k++) wcol[k]=W_pe[k*256 + h*64 + c];
      const float bpr = Bpre[(size_t)t*256 + h*64 + c];
      for(int m=0;m<50;m++){
        int n=n0+m*8;
        float a = Apre[(size_t)n*256 + h*64 + c] + bpr;
        #pragma unroll
        for(int k=0;k<32;k++) a += sP1[n][k]*wcol[k];
        s_h[n][c]=f2bf(a);
      }
    }
    if(tid<NN){
      float sa=Aal_s[tid*4+h]+Bal_s[t*4+h];
      float da=Aal_d[tid*4+h]+Bal_d[t*4+h];
      #pragma unroll
      for(int k=0;k<32;k++){ float p=sP1[tid][k]; sa+=p*wpe_s[k*4+h]; da+=p*wpe_d[k*4+h]; }
      s_als[tid]=sa; s_ald[tid]=da;
    }
    __syncthreads();
    edge_softmax(tid,s_rp,s_col,s_als,s_ald,s_alpha);
    __syncthreads();
    if(tid<NN){
      int b=s_rp[tid], en=s_rp[tid+1];
      for(int j=b;j<en;j++){
        float a=s_alpha[j]; int s=s_col[j];
        #pragma unroll
        for(int cc=0;cc<64;cc++) r[cc]+=a*bf2f(s_h[s][cc]);
      }
    }
    __syncthreads();
  }
  // g1 = relu(mean(heads)+bt1) -> s_g (overwrites sP1; last sP1 read was before the barrier)
  if(tid<NN){
    #pragma unroll
    for(int cc=0;cc<64;cc++) s_g[tid][cc]=f2bf(fmaxf(0.25f*r[cc]+bt1[cc],0.f));
  }
  __syncthreads();

  // ======== temporal GAT layer 2 (1 head) ========
  {
    float wcol[64];
    #pragma unroll
    for(int k=0;k<64;k++) wcol[k]=Wt2[k*64+c];
    for(int m=0;m<50;m++){
      int n=n0+m*8;
      float a=0.f;
      #pragma unroll
      for(int k=0;k<64;k++) a+=bf2f(s_g[n][k])*wcol[k];
      s_h[n][c]=f2bf(a);
    }
  }
  if(tid<NN){
    float sa=0.f,da=0.f;
    #pragma unroll
    for(int k=0;k<64;k++){ float g=bf2f(s_g[tid][k]); sa+=g*w2s[k]; da+=g*w2d[k]; }
    s_als[tid]=sa; s_ald[tid]=da;
  }
  __syncthreads();
  edge_softmax(tid,s_rp,s_col,s_als,s_ald,s_alpha);
  __syncthreads();
  float Hrow[64];
  if(tid<NN){
    #pragma unroll
    for(int cc=0;cc<64;cc++) Hrow[cc]=0.f;
    int b=s_rp[tid], en=s_rp[tid+1];
    for(int j=b;j<en;j++){
      float a=s_alpha[j]; int s=s_col[j];
      #pragma unroll
      for(int cc=0;cc<64;cc++) Hrow[cc]+=a*bf2f(s_h[s][cc]);
    }
    #pragma unroll
    for(int cc=0;cc<64;cc++) Hrow[cc]=fmaxf(Hrow[cc]+bt2[cc],0.f);
    float* hp=Hout+((size_t)t*NN+tid)*64;
    #pragma unroll
    for(int cc=0;cc<64;cc++) hp[cc]=Hrow[cc];
  }
  __syncthreads();
  if(tid<NN){
    #pragma unroll
    for(int cc=0;cc<64;cc++) s_g[tid][cc]=f2bf(Hrow[cc]);
  }
  __syncthreads();

  // ======== head MLP: pj = relu(H@Wh1+bh1); pred = pj@Wh2+bh2 ========
  {
    const int j=tid&31;
    float whcol[64];
    #pragma unroll
    for(int cc=0;cc<64;cc++) whcol[cc]=Wh1[cc*32+j];
    const float bj=bh1[j];
    for(int m=0;m<25;m++){
      int n=(tid>>5)+m*16;
      float a=bj;
      #pragma unroll
      for(int cc=0;cc<64;cc++) a+=bf2f(s_g[n][cc])*whcol[cc];
      pjp[n*33+j]=fmaxf(a,0.f);
    }
  }
  __syncthreads();
  if(tid<NN){
    float a=bh2[0];
    #pragma unroll
    for(int jj=0;jj<32;jj++) a+=pjp[tid*33+jj]*Wh2[jj];
    pred[(size_t)t*NN+tid]=a;
  }
}

extern "C" void kernel_launch(void* const* d_in, const int* in_sizes, int n_in,
                              void* d_out, int out_size, void* d_ws, size_t ws_size,
                              hipStream_t stream) {
  const float* x_static=(const float*)d_in[0];
  const float* pf      =(const float*)d_in[1];
  const int*   ei      =(const int*)  d_in[2];
  const float* Ws1=(const float*)d_in[3];
  const float* as1_src=(const float*)d_in[4];
  const float* as1_dst=(const float*)d_in[5];
  const float* bs1=(const float*)d_in[6];
  const float* Ws2=(const float*)d_in[7];
  const float* as2_src=(const float*)d_in[8];
  const float* as2_dst=(const float*)d_in[9];
  const float* bs2=(const float*)d_in[10];
  const float* wd_emb=(const float*)d_in[11];
  const float* sl_emb=(const float*)d_in[12];
  const float* Wc1=(const float*)d_in[13];
  const float* bc1=(const float*)d_in[14];
  const float* Wc2=(const float*)d_in[15];
  const float* bc2=(const float*)d_in[16];
  const float* Wp1=(const float*)d_in[17];
  const float* bp1=(const float*)d_in[18];
  const float* Wp2=(const float*)d_in[19];
  const float* bp2=(const float*)d_in[20];
  const float* Wt1=(const float*)d_in[21];
  const float* at1_src=(const float*)d_in[22];
  const float* at1_dst=(const float*)d_in[23];
  const float* bt1=(const float*)d_in[24];
  const float* Wt2=(const float*)d_in[25];
  const float* at2_src=(const float*)d_in[26];
  const float* at2_dst=(const float*)d_in[27];
  const float* bt2=(const float*)d_in[28];
  const float* Wh1=(const float*)d_in[29];
  const float* bh1=(const float*)d_in[30];
  const float* Wh2=(const float*)d_in[31];
  const float* bh2=(const float*)d_in[32];

  float* Hout=(float*)d_out;
  float* pred=Hout + (size_t)TT*NN*64;

  char* w=(char*)d_ws; size_t off=0;
  auto A=[&](size_t n)->void*{ void* p=w+off; off=(off+n+255)&~(size_t)255; return p; };
  float* xs    =(float*)A((size_t)NN*32*4);
  float* Apre  =(float*)A((size_t)NN*256*4);
  float* Aal_s =(float*)A((size_t)NN*4*4);
  float* Aal_d =(float*)A((size_t)NN*4*4);
  float* Bpre  =(float*)A((size_t)TT*256*4);
  float* Bal_s =(float*)A((size_t)TT*4*4);
  float* Bal_d =(float*)A((size_t)TT*4*4);
  float* W_pe  =(float*)A(32*256*4);
  float* b_pe  =(float*)A(256*4);
  float* wpe_s =(float*)A(32*4*4);
  float* wpe_d =(float*)A(32*4*4);
  float* wt1_as=(float*)A(32*4*4);
  float* wt1_ad=(float*)A(32*4*4);
  float* w2s   =(float*)A(64*4);
  float* w2d   =(float*)A(64*4);
  int* row_ptr =(int*)A((NN+1)*4);
  int* col_src =(int*)A(NE*4);

  hipLaunchKernelGGL(k_csr, dim3(1), dim3(1024), 0, stream, ei, row_ptr, col_src);
  hipLaunchKernelGGL(k_wpe, dim3(1), dim3(256), 0, stream,
                     Wp2,bp2,Wt1,at1_src,at1_dst,Wt2,at2_src,at2_dst,
                     W_pe,b_pe,wpe_s,wpe_d,wt1_as,wt1_ad,w2s,w2d);
  hipLaunchKernelGGL(k_static, dim3(1), dim3(512), 0, stream,
                     x_static,Ws1,as1_src,as1_dst,bs1,Ws2,as2_src,as2_dst,bs2,
                     row_ptr,col_src,xs);
  hipLaunchKernelGGL(k_cal, dim3(TT), dim3(256), 0, stream,
                     wd_emb,sl_emb,Wc1,bc1,Wc2,bc2,Wt1,at1_src,at1_dst,b_pe,
                     Bpre,Bal_s,Bal_d);
  hipLaunchKernelGGL(k_apre, dim3(NN), dim3(256), 0, stream,
                     xs,Wt1,wt1_as,wt1_ad,Apre,Aal_s,Aal_d);
  hipLaunchKernelGGL(k_temporal, dim3(TT), dim3(512), 0, stream,
                     pf,Wp1,bp1,Apre,Aal_s,Aal_d,Bpre,Bal_s,Bal_d,
                     W_pe,wpe_s,wpe_d,bt1,
                     Wt2,w2s,w2d,bt2,Wh1,bh1,Wh2,bh2,
                     row_ptr,col_src,Hout,pred);
}

// Round 2
// 918.377 us; speedup vs baseline: 1.9842x; 1.9842x over previous
//
#include <hip/hip_runtime.h>

typedef unsigned short u16;
typedef unsigned int   u32;
typedef __attribute__((ext_vector_type(8))) short bf16x8;
typedef __attribute__((ext_vector_type(4))) float f32x4;

#define NN  400
#define EIN 3200
#define NE  3600
#define TT  2016

__device__ __forceinline__ float bf2f(u16 h){
  union{u32 u; float f;} v; v.u=((u32)h)<<16; return v.f;
}
__device__ __forceinline__ u16 f2bf(float f){
  union{float f; u32 u;} v; v.f=f;
  u32 r=v.u + 0x7FFFu + ((v.u>>16)&1u);
  return (u16)(r>>16);
}
__device__ __forceinline__ float blo(u32 w){ union{u32 u; float f;} v; v.u=w<<16; return v.f; }
__device__ __forceinline__ float bhi(u32 w){ union{u32 u; float f;} v; v.u=w&0xffff0000u; return v.f; }
__device__ __forceinline__ float lrelu(float x){ return x>0.f ? x : 0.2f*x; }

// ---------------- CSR build + degree-sorted dst order (deterministic) ----------------
__global__ __launch_bounds__(1024) void k_csr(const int* __restrict__ ei,
                                              u16* __restrict__ rp_out,
                                              u16* __restrict__ col_out,
                                              u16* __restrict__ ord_out){
  __shared__ int s_dst[NE];
  __shared__ int s_deg[NN];
  __shared__ int s_rp[NN+1];
  int tid=threadIdx.x;
  for(int e=tid;e<NE;e+=1024)
    s_dst[e] = (e<EIN) ? ei[EIN+e] : (e-EIN);   // self loops appended
  __syncthreads();
  for(int d=tid;d<NN;d+=1024){
    int c=0;
    for(int j=0;j<NE;j++) c += (s_dst[j]==d);
    s_deg[d]=c;
  }
  __syncthreads();
  for(int d=tid;d<=NN;d+=1024){
    int acc=0;
    for(int j=0;j<d;j++) acc+=s_deg[j];
    s_rp[d]=acc;
    rp_out[d]=(u16)acc;
  }
  if(tid==0) rp_out[NN+1]=(u16)NE;  // pad so u32 staging reads defined data
  __syncthreads();
  for(int e=tid;e<NE;e+=1024){
    int dd=s_dst[e];
    int rank=0;
    for(int j=0;j<e;j++) rank += (s_dst[j]==dd);
    int sv = (e<EIN) ? ei[e] : (e-EIN);
    col_out[s_rp[dd]+rank]=(u16)sv;
  }
  // descending-degree order (tie: smaller node id first) -> balances group divergence
  for(int d=tid;d<NN;d+=1024){
    int dg=s_deg[d];
    int rk=0;
    for(int j=0;j<NN;j++) rk += (s_deg[j]>dg) || (s_deg[j]==dg && j<d);
    ord_out[rk]=(u16)d;
  }
}

// ---------------- weight folds + MFMA B-fragment packing ----------------
__global__ __launch_bounds__(256) void k_prep(
    const float* __restrict__ Wp2, const float* __restrict__ bp2,
    const float* __restrict__ Wt1,
    const float* __restrict__ at1_src, const float* __restrict__ at1_dst,
    const float* __restrict__ Wt2, const float* __restrict__ at2_src, const float* __restrict__ at2_dst,
    const float* __restrict__ Wh1,
    float* __restrict__ W_pe, float* __restrict__ b_pe,
    float* __restrict__ wpe_s, float* __restrict__ wpe_d,
    float* __restrict__ wt1_as, float* __restrict__ wt1_ad,
    float* __restrict__ w2s, float* __restrict__ w2d,
    u16* __restrict__ Bf1, u16* __restrict__ Bf2, u16* __restrict__ Bfh)
{
  int tid=threadIdx.x;
  for(int i=tid;i<32*256;i+=256){
    int k=i>>8, j=i&255;
    float a=0.f;
    for(int m=0;m<32;m++) a+=Wp2[k*32+m]*Wt1[(64+m)*256+j];
    W_pe[i]=a;
  }
  { int j=tid;
    float a=0.f;
    for(int m=0;m<32;m++) a+=bp2[m]*Wt1[(64+m)*256+j];
    b_pe[j]=a; }
  __syncthreads();
  if(tid<128){
    int k=tid>>2, h=tid&3;
    float s=0.f,d=0.f;
    for(int c=0;c<64;c++){ float wv=W_pe[k*256+h*64+c]; s+=wv*at1_src[h*64+c]; d+=wv*at1_dst[h*64+c]; }
    wpe_s[tid]=s; wpe_d[tid]=d;
    float s2=0.f,d2=0.f;
    for(int c=0;c<64;c++){ float wv=Wt1[k*256+h*64+c]; s2+=wv*at1_src[h*64+c]; d2+=wv*at1_dst[h*64+c]; }
    wt1_as[tid]=s2; wt1_ad[tid]=d2;
  }
  if(tid>=128 && tid<192){
    int k=tid-128;
    float s=0.f,d=0.f;
    for(int c=0;c<64;c++){ float wv=Wt2[k*64+c]; s+=wv*at2_src[c]; d+=wv*at2_dst[c]; }
    w2s[k]=s; w2d[k]=d;
  }
  __syncthreads();
  // Bf1: [h4][nt4][ks2][lane64][j8]; A row = [P1(32) | xs(32)]; W rows: k<32 -> W_pe, k>=32 -> Wt1[k-32]
  for(int i=tid;i<16384;i+=256){
    int j=i&7, ll=(i>>3)&63, ks=(i>>9)&1, nt=(i>>10)&3, h=(i>>12)&3;
    int k = ks*32 + (ll>>4)*8 + j;
    int c = h*64 + nt*16 + (ll&15);
    float v = (k<32) ? W_pe[k*256+c] : Wt1[(k-32)*256+c];
    Bf1[i]=f2bf(v);
  }
  // Bf2: [nt4][ks2][64][8] from Wt2 (64x64)
  for(int i=tid;i<4096;i+=256){
    int j=i&7, ll=(i>>3)&63, ks=(i>>9)&1, nt=(i>>10)&3;
    int k = ks*32 + (ll>>4)*8 + j;
    int c = nt*16 + (ll&15);
    Bf2[i]=f2bf(Wt2[k*64+c]);
  }
  // Bfh: [nt2][ks2][64][8] from Wh1 (64x32)
  for(int i=tid;i<2048;i+=256){
    int j=i&7, ll=(i>>3)&63, ks=(i>>9)&1, nt=(i>>10)&1;
    int k = ks*32 + (ll>>4)*8 + j;
    int c = nt*16 + (ll&15);
    Bfh[i]=f2bf(Wh1[k*32+c]);
  }
}

// per-dst edge softmax over CSR rows (f32, for static encoder)
__device__ __forceinline__ void edge_softmax(int tid, const int* s_rp, const int* s_col,
                                             const float* s_als, const float* s_ald,
                                             float* s_alpha){
  if(tid<NN){
    int b=s_rp[tid], en=s_rp[tid+1];
    float ad=s_ald[tid];
    float mx=-1e30f;
    for(int j=b;j<en;j++){ float v=lrelu(s_als[s_col[j]]+ad); s_alpha[j]=v; mx=fmaxf(mx,v); }
    float den=0.f;
    for(int j=b;j<en;j++){ float ex=__expf(s_alpha[j]-mx); s_alpha[j]=ex; den+=ex; }
    float inv=1.f/den;
    for(int j=b;j<en;j++) s_alpha[j]*=inv;
  }
}

// ---------------- static 2-layer GAT (single block) ----------------
__global__ __launch_bounds__(512) void k_static(
    const float* __restrict__ x_static,
    const float* __restrict__ Ws1, const float* __restrict__ as1_src, const float* __restrict__ as1_dst, const float* __restrict__ bs1,
    const float* __restrict__ Ws2, const float* __restrict__ as2_src, const float* __restrict__ as2_dst, const float* __restrict__ bs2,
    const u16* __restrict__ rp_in, const u16* __restrict__ col_in,
    float* __restrict__ xs)
{
  __shared__ float s_x[NN][32];
  __shared__ float s_h[NN][33];
  __shared__ float s_als[NN], s_ald[NN];
  __shared__ float s_alpha[NE];
  __shared__ int   s_col[NE];
  __shared__ int   s_rp[NN+1];
  int tid=threadIdx.x;
  for(int i=tid;i<NE;i+=512) s_col[i]=(int)col_in[i];
  if(tid<NN+1) s_rp[tid]=(int)rp_in[tid];
  for(int i=tid;i<NN*16;i+=512) s_x[i>>4][i&15]=x_static[i];
  __syncthreads();
  float r[32];
  #pragma unroll
  for(int cc=0;cc<32;cc++) r[cc]=0.f;
  for(int h=0;h<4;h++){
    for(int i=tid;i<NN*32;i+=512){
      int n=i>>5, cc=i&31;
      float a=0.f;
      #pragma unroll
      for(int k=0;k<16;k++) a+=s_x[n][k]*Ws1[k*128+h*32+cc];
      s_h[n][cc]=a;
    }
    __syncthreads();
    if(tid<NN){
      float sa=0.f,da=0.f;
      #pragma unroll
      for(int cc=0;cc<32;cc++){ float hv=s_h[tid][cc]; sa+=hv*as1_src[h*32+cc]; da+=hv*as1_dst[h*32+cc]; }
      s_als[tid]=sa; s_ald[tid]=da;
    }
    __syncthreads();
    edge_softmax(tid,s_rp,s_col,s_als,s_ald,s_alpha);
    __syncthreads();
    if(tid<NN){
      int b=s_rp[tid], en=s_rp[tid+1];
      for(int j=b;j<en;j++){
        float a=s_alpha[j]; int s=s_col[j];
        #pragma unroll
        for(int cc=0;cc<32;cc++) r[cc]+=a*s_h[s][cc];
      }
    }
    __syncthreads();
  }
  if(tid<NN){
    #pragma unroll
    for(int cc=0;cc<32;cc++) s_x[tid][cc]=fmaxf(0.25f*r[cc]+bs1[cc],0.f);
  }
  __syncthreads();
  #pragma unroll
  for(int cc=0;cc<32;cc++) r[cc]=0.f;
  for(int i=tid;i<NN*32;i+=512){
    int n=i>>5, cc=i&31;
    float a=0.f;
    #pragma unroll
    for(int k=0;k<32;k++) a+=s_x[n][k]*Ws2[k*32+cc];
    s_h[n][cc]=a;
  }
  __syncthreads();
  if(tid<NN){
    float sa=0.f,da=0.f;
    #pragma unroll
    for(int cc=0;cc<32;cc++){ float hv=s_h[tid][cc]; sa+=hv*as2_src[cc]; da+=hv*as2_dst[cc]; }
    s_als[tid]=sa; s_ald[tid]=da;
  }
  __syncthreads();
  edge_softmax(tid,s_rp,s_col,s_als,s_ald,s_alpha);
  __syncthreads();
  if(tid<NN){
    int b=s_rp[tid], en=s_rp[tid+1];
    for(int j=b;j<en;j++){
      float a=s_alpha[j]; int s=s_col[j];
      #pragma unroll
      for(int cc=0;cc<32;cc++) r[cc]+=a*s_h[s][cc];
    }
    #pragma unroll
    for(int cc=0;cc<32;cc++) xs[tid*32+cc]=fmaxf(r[cc]+bs2[cc],0.f);
  }
}

// ---------------- calendar path: Bpre[t,256], Bal_{s,d}[t,4] ----------------
__global__ __launch_bounds__(256) void k_cal(
    const float* __restrict__ wd_emb, const float* __restrict__ sl_emb,
    const float* __restrict__ Wc1, const float* __restrict__ bc1,
    const float* __restrict__ Wc2, const float* __restrict__ bc2,
    const float* __restrict__ Wt1,
    const float* __restrict__ at1_src, const float* __restrict__ at1_dst,
    const float* __restrict__ b_pe,
    float* __restrict__ Bpre, float* __restrict__ Bal_s, float* __restrict__ Bal_d)
{
  const double PI=3.14159265358979323846;
  int t=blockIdx.x; int wd=t/288, sl=t%288; int tid=threadIdx.x;
  __shared__ float feat[32];
  __shared__ float c1[32];
  __shared__ float calv[32];
  __shared__ float bpre[256];
  if(tid<8) feat[tid]=wd_emb[wd*8+tid];
  if(tid>=8 && tid<24) feat[tid]=sl_emb[sl*16+(tid-8)];
  if(tid==24||tid==25){ float ta=(float)(2.0*PI/288.0)*(float)sl; feat[tid]=(tid==24)?sinf(ta):cosf(ta); }
  if(tid==26||tid==27){ float wa=(float)(2.0*PI/7.0)*(float)wd;   feat[tid]=(tid==26)?sinf(wa):cosf(wa); }
  if(tid==28) feat[28]=(wd>=5)?1.f:0.f;
  __syncthreads();
  if(tid<32){ float a=bc1[tid]; for(int k=0;k<29;k++) a+=feat[k]*Wc1[k*32+tid]; c1[tid]=fmaxf(a,0.f); }
  __syncthreads();
  if(tid<32){ float a=bc2[tid]; for(int k=0;k<32;k++) a+=c1[k]*Wc2[k*32+tid]; calv[tid]=a; }
  __syncthreads();
  { int j=tid; float a=b_pe[j];
    for(int k=0;k<32;k++) a+=calv[k]*Wt1[(32+k)*256+j];
    bpre[j]=a; Bpre[(size_t)t*256+j]=a; }
  __syncthreads();
  if(tid<8){ int hh=tid&3; const float* av=(tid<4)?at1_src:at1_dst;
    float a=0.f;
    for(int cc=0;cc<64;cc++) a+=bpre[hh*64+cc]*av[hh*64+cc];
    if(tid<4) Bal_s[t*4+hh]=a; else Bal_d[t*4+hh]=a; }
}

// ---------------- xs: pack bf16 + fold attention logit (xs part) ----------------
__global__ __launch_bounds__(512) void k_xs(const float* __restrict__ xs,
    const float* __restrict__ wt1_as, const float* __restrict__ wt1_ad,
    u32* __restrict__ xsb, float* __restrict__ Aal_s, float* __restrict__ Aal_d)
{
  int n=threadIdx.x;
  if(n<NN){
    float v[32];
    #pragma unroll
    for(int k=0;k<32;k++) v[k]=xs[n*32+k];
    #pragma unroll
    for(int h=0;h<4;h++){
      float s=0.f,d=0.f;
      #pragma unroll
      for(int k=0;k<32;k++){ s+=v[k]*wt1_as[k*4+h]; d+=v[k]*wt1_ad[k*4+h]; }
      Aal_s[n*4+h]=s; Aal_d[n*4+h]=d;
    }
    #pragma unroll
    for(int q=0;q<16;q++)
      xsb[n*16+q] = (u32)f2bf(v[2*q]) | ((u32)f2bf(v[2*q+1])<<16);
  }
}

// ---------------- fused temporal kernel ----------------
// LDS carve (rows padded to 144B so MFMA fragment b128 reads are conflict-free)
#define OFF_A   0        // u16 [400][72]: cols 0-31 P1 bf16, 32-63 xs bf16; aliased g1 / H later
#define OFF_H   57600    // u16 [400][72]: per-head h1 / h2; later pj f32 [400][36]
#define OFF_ALS 115200   // f32 [400][4] (layer1), f32 [400] (layer2)
#define OFF_ALD 121600
#define OFF_COL 128000   // u16 [3600]
#define OFF_RP  135200   // u16 [402]+pad
#define OFF_ORD 136008   // u16 [400]
#define OFF_BP  136808   // f32 [256]
#define SMEM_SZ 137832

__global__ __launch_bounds__(1024) void k_temporal(
    const float* __restrict__ pf, const float* __restrict__ Wp1, const float* __restrict__ bp1,
    const u32*  __restrict__ xsb,
    const float* __restrict__ Aal_s, const float* __restrict__ Aal_d,
    const float* __restrict__ Bpre, const float* __restrict__ Bal_s, const float* __restrict__ Bal_d,
    const float* __restrict__ wpe_s, const float* __restrict__ wpe_d,
    const u16* __restrict__ Bf1, const u16* __restrict__ Bf2, const u16* __restrict__ Bfh,
    const float* __restrict__ bt1, const float* __restrict__ w2s, const float* __restrict__ w2d,
    const float* __restrict__ bt2, const float* __restrict__ bh1,
    const float* __restrict__ Wh2, const float* __restrict__ bh2,
    const u16* __restrict__ g_rp, const u16* __restrict__ g_col, const u16* __restrict__ g_ord,
    float* __restrict__ Hout, float* __restrict__ pred)
{
  __shared__ __align__(16) char smem[SMEM_SZ];
  float* S_ALS = (float*)(smem+OFF_ALS);
  float* S_ALD = (float*)(smem+OFF_ALD);
  u16*   S_COL = (u16*)(smem+OFF_COL);
  u16*   S_RP  = (u16*)(smem+OFF_RP);
  u16*   S_ORD = (u16*)(smem+OFF_ORD);
  float* S_BP  = (float*)(smem+OFF_BP);

  const int t=blockIdx.x, tid=threadIdx.x;
  const int l = tid & 63;
  const int w = tid >> 6;          // wave 0..15
  const int lane8 = tid & 7, grp = tid >> 3;   // 128 groups of 8
  const int col16 = l & 15;
  const int cr = (l >> 4) * 4;     // C-frag row base
  const int kbyte = (l >> 4) * 16; // A-frag k-chunk byte offset

  // prefetch pf row (8 f32)
  float4 pA = make_float4(0,0,0,0), pB = make_float4(0,0,0,0);
  if (tid < NN){
    const float4* pp = (const float4*)(pf + ((size_t)tid*TT + (size_t)t)*8);
    pA = pp[0]; pB = pp[1];
  }
  // stage edge structures / Bpre row
  for (int i=tid;i<1800;i+=1024) ((u32*)S_COL)[i] = ((const u32*)g_col)[i];
  for (int i=tid;i<201;i+=1024)  ((u32*)S_RP)[i]  = ((const u32*)g_rp)[i];
  for (int i=tid;i<200;i+=1024)  ((u32*)S_ORD)[i] = ((const u32*)g_ord)[i];
  for (int i=tid;i<256;i+=1024)  S_BP[i] = Bpre[(size_t)t*256+i];
  // xs -> s_a cols 32..63
  for (int i=tid;i<NN*16;i+=1024){
    int n=i>>4, q=i&15;
    *(u32*)(smem + OFF_A + n*144 + 64 + q*4) = xsb[i];
  }
  // P1 = relu(pf@Wp1+bp1) -> s_a cols 0..31 (bf16 packed)
  if (tid < NN){
    float px[8] = {pA.x,pA.y,pA.z,pA.w,pB.x,pB.y,pB.z,pB.w};
    #pragma unroll
    for (int q=0;q<16;q++){
      float a0 = bp1[2*q], a1 = bp1[2*q+1];
      #pragma unroll
      for (int i2=0;i2<8;i2++){ a0 += px[i2]*Wp1[i2*32+2*q]; a1 += px[i2]*Wp1[i2*32+2*q+1]; }
      a0 = fmaxf(a0,0.f); a1 = fmaxf(a1,0.f);
      *(u32*)(smem + OFF_A + tid*144 + q*4) = (u32)f2bf(a0) | ((u32)f2bf(a1)<<16);
    }
  }
  __syncthreads();

  // logits, all 4 heads (visibility covered by the matmul barrier below)
  if (tid < NN){
    float pv[32];
    const u32* pr = (const u32*)(smem + OFF_A + tid*144);
    #pragma unroll
    for (int q=0;q<16;q++){ u32 v=pr[q]; pv[2*q]=blo(v); pv[2*q+1]=bhi(v); }
    #pragma unroll
    for (int h=0;h<4;h++){
      float sa = Aal_s[tid*4+h] + Bal_s[(size_t)t*4+h];
      float da = Aal_d[tid*4+h] + Bal_d[(size_t)t*4+h];
      #pragma unroll
      for (int k=0;k<32;k++){ sa += pv[k]*wpe_s[k*4+h]; da += pv[k]*wpe_d[k*4+h]; }
      S_ALS[tid*4+h]=sa; S_ALD[tid*4+h]=da;
    }
  }

  float acc[4][8];
  #pragma unroll
  for (int m=0;m<4;m++){
    #pragma unroll
    for (int q=0;q<8;q++) acc[m][q]=0.f;
  }

  // ======== temporal GAT layer 1 (4 heads) ========
  for (int h=0;h<4;h++){
    // MFMA: h1 (head h) = [P1|xs] @ Bf1_h + Bpre  -> S_H bf16
    for (int mt=w; mt<25; mt+=16){
      const char* arow = smem + OFF_A + (mt*16+col16)*144;
      bf16x8 a0 = *(const bf16x8*)(arow + kbyte);
      bf16x8 a1 = *(const bf16x8*)(arow + 64 + kbyte);
      #pragma unroll
      for (int nt=0;nt<4;nt++){
        float bp = S_BP[h*64 + nt*16 + col16];
        f32x4 c = {bp,bp,bp,bp};
        bf16x8 b0 = *(const bf16x8*)(Bf1 + (((h*4+nt)*2+0)*512 + l*8));
        bf16x8 b1 = *(const bf16x8*)(Bf1 + (((h*4+nt)*2+1)*512 + l*8));
        c = __builtin_amdgcn_mfma_f32_16x16x32_bf16(a0,b0,c,0,0,0);
        c = __builtin_amdgcn_mfma_f32_16x16x32_bf16(a1,b1,c,0,0,0);
        #pragma unroll
        for (int r=0;r<4;r++)
          *(u16*)(smem + OFF_H + (mt*16+cr+r)*144 + (nt*16+col16)*2) = f2bf(c[r]);
      }
    }
    __syncthreads();
    // fused softmax + aggregation (8 lanes per dst, channel-split)
    #pragma unroll
    for (int m=0;m<4;m++){
      int di = grp + m*128;
      float rt[8];
      #pragma unroll
      for (int q=0;q<8;q++) rt[q]=0.f;
      float inv = 0.f;
      if (di < NN){
        int d = S_ORD[di];
        int b = S_RP[d], e = S_RP[d+1];
        float ad = S_ALD[d*4+h];
        float mx = -1e30f;
        for (int j=b+lane8; j<e; j+=8)
          mx = fmaxf(mx, lrelu(S_ALS[(int)S_COL[j]*4+h] + ad));
        mx = fmaxf(mx, __shfl_xor(mx,1));
        mx = fmaxf(mx, __shfl_xor(mx,2));
        mx = fmaxf(mx, __shfl_xor(mx,4));
        float den = 0.f;
        for (int j=b; j<e; j++){
          int s = S_COL[j];
          float p = __expf(lrelu(S_ALS[s*4+h]+ad) - mx);
          den += p;
          uint4 hw = *(const uint4*)(smem + OFF_H + s*144 + lane8*16);
          rt[0]+=p*blo(hw.x); rt[1]+=p*bhi(hw.x);
          rt[2]+=p*blo(hw.y); rt[3]+=p*bhi(hw.y);
          rt[4]+=p*blo(hw.z); rt[5]+=p*bhi(hw.z);
          rt[6]+=p*blo(hw.w); rt[7]+=p*bhi(hw.w);
        }
        inv = 1.f/den;
      }
      #pragma unroll
      for (int q=0;q<8;q++) acc[m][q] += rt[q]*inv;
    }
    __syncthreads();
  }

  // g1 = relu(0.25*acc + bt1) -> S_A (alias; P1/xs dead)
  #pragma unroll
  for (int m=0;m<4;m++){
    int di = grp + m*128;
    if (di < NN){
      int d = S_ORD[di];
      u32 pk[4];
      #pragma unroll
      for (int q=0;q<4;q++){
        float v0 = fmaxf(0.25f*acc[m][2*q]   + bt1[lane8*8+2*q],   0.f);
        float v1 = fmaxf(0.25f*acc[m][2*q+1] + bt1[lane8*8+2*q+1], 0.f);
        pk[q] = (u32)f2bf(v0) | ((u32)f2bf(v1)<<16);
      }
      *(uint4*)(smem + OFF_A + d*144 + lane8*16) = make_uint4(pk[0],pk[1],pk[2],pk[3]);
    }
  }
  __syncthreads();

  // ======== temporal GAT layer 2 (1 head) ========
  for (int mt=w; mt<25; mt+=16){
    const char* arow = smem + OFF_A + (mt*16+col16)*144;
    bf16x8 a0 = *(const bf16x8*)(arow + kbyte);
    bf16x8 a1 = *(const bf16x8*)(arow + 64 + kbyte);
    #pragma unroll
    for (int nt=0;nt<4;nt++){
      f32x4 c = {0.f,0.f,0.f,0.f};
      bf16x8 b0 = *(const bf16x8*)(Bf2 + ((nt*2+0)*512 + l*8));
      bf16x8 b1 = *(const bf16x8*)(Bf2 + ((nt*2+1)*512 + l*8));
      c = __builtin_amdgcn_mfma_f32_16x16x32_bf16(a0,b0,c,0,0,0);
      c = __builtin_amdgcn_mfma_f32_16x16x32_bf16(a1,b1,c,0,0,0);
      #pragma unroll
      for (int r=0;r<4;r++)
        *(u16*)(smem + OFF_H + (mt*16+cr+r)*144 + (nt*16+col16)*2) = f2bf(c[r]);
    }
  }
  // logits2 from g1 (folded Wt2·a2)
  #pragma unroll
  for (int m=0;m<4;m++){
    int di = grp + m*128;
    if (di < NN){
      int d = S_ORD[di];
      uint4 gv = *(const uint4*)(smem + OFF_A + d*144 + lane8*16);
      u32 wv[4] = {gv.x,gv.y,gv.z,gv.w};
      float ss=0.f, dd=0.f;
      #pragma unroll
      for (int q=0;q<4;q++){
        int c0 = lane8*8 + 2*q;
        float g0=blo(wv[q]), g1=bhi(wv[q]);
        ss += g0*w2s[c0] + g1*w2s[c0+1];
        dd += g0*w2d[c0] + g1*w2d[c0+1];
      }
      ss += __shfl_xor(ss,1); ss += __shfl_xor(ss,2); ss += __shfl_xor(ss,4);
      dd += __shfl_xor(dd,1); dd += __shfl_xor(dd,2); dd += __shfl_xor(dd,4);
      if (lane8==0){ S_ALS[d]=ss; S_ALD[d]=dd; }
    }
  }
  __syncthreads();
  // softmax+agg layer2 -> H (global f32) + S_A (bf16 for head MLP)
  #pragma unroll
  for (int m=0;m<4;m++){
    int di = grp + m*128;
    if (di < NN){
      int d = S_ORD[di];
      int b = S_RP[d], e = S_RP[d+1];
      float ad = S_ALD[d];
      float mx = -1e30f;
      for (int j=b+lane8; j<e; j+=8)
        mx = fmaxf(mx, lrelu(S_ALS[(int)S_COL[j]] + ad));
      mx = fmaxf(mx, __shfl_xor(mx,1));
      mx = fmaxf(mx, __shfl_xor(mx,2));
      mx = fmaxf(mx, __shfl_xor(mx,4));
      float den=0.f;
      float rt[8];
      #pragma unroll
      for (int q=0;q<8;q++) rt[q]=0.f;
      for (int j=b; j<e; j++){
        int s = S_COL[j];
        float p = __expf(lrelu(S_ALS[s]+ad) - mx);
        den += p;
        uint4 hw = *(const uint4*)(smem + OFF_H + s*144 + lane8*16);
        rt[0]+=p*blo(hw.x); rt[1]+=p*bhi(hw.x);
        rt[2]+=p*blo(hw.y); rt[3]+=p*bhi(hw.y);
        rt[4]+=p*blo(hw.z); rt[5]+=p*bhi(hw.z);
        rt[6]+=p*blo(hw.w); rt[7]+=p*bhi(hw.w);
      }
      float inv = 1.f/den;
      float hv[8];
      #pragma unroll
      for (int q=0;q<8;q++) hv[q] = fmaxf(rt[q]*inv + bt2[lane8*8+q], 0.f);
      float* hp = Hout + ((size_t)t*NN + d)*64 + lane8*8;
      *(float4*)(hp)   = make_float4(hv[0],hv[1],hv[2],hv[3]);
      *(float4*)(hp+4) = make_float4(hv[4],hv[5],hv[6],hv[7]);
      u32 pk0 = (u32)f2bf(hv[0]) | ((u32)f2bf(hv[1])<<16);
      u32 pk1 = (u32)f2bf(hv[2]) | ((u32)f2bf(hv[3])<<16);
      u32 pk2 = (u32)f2bf(hv[4]) | ((u32)f2bf(hv[5])<<16);
      u32 pk3 = (u32)f2bf(hv[6]) | ((u32)f2bf(hv[7])<<16);
      *(uint4*)(smem + OFF_A + d*144 + lane8*16) = make_uint4(pk0,pk1,pk2,pk3);
    }
  }
  __syncthreads();

  // ======== head MLP: pj = relu(H@Wh1+bh1) -> S_H f32; pred = pj@Wh2+bh2 ========
  for (int mt=w; mt<25; mt+=16){
    const char* arow = smem + OFF_A + (mt*16+col16)*144;
    bf16x8 a0 = *(const bf16x8*)(arow + kbyte);
    bf16x8 a1 = *(const bf16x8*)(arow + 64 + kbyte);
    #pragma unroll
    for (int nt=0;nt<2;nt++){
      float bj = bh1[nt*16+col16];
      f32x4 c = {bj,bj,bj,bj};
      bf16x8 b0 = *(const bf16x8*)(Bfh + ((nt*2+0)*512 + l*8));
      bf16x8 b1 = *(const bf16x8*)(Bfh + ((nt*2+1)*512 + l*8));
      c = __builtin_amdgcn_mfma_f32_16x16x32_bf16(a0,b0,c,0,0,0);
      c = __builtin_amdgcn_mfma_f32_16x16x32_bf16(a1,b1,c,0,0,0);
      #pragma unroll
      for (int r=0;r<4;r++)
        *(float*)(smem + OFF_H + (mt*16+cr+r)*144 + (nt*16+col16)*4) = fmaxf(c[r],0.f);
    }
  }
  __syncthreads();
  {
    float wv0=Wh2[lane8*4+0], wv1=Wh2[lane8*4+1], wv2=Wh2[lane8*4+2], wv3=Wh2[lane8*4+3];
    float bb = bh2[0];
    #pragma unroll
    for (int m=0;m<4;m++){
      int di = grp + m*128;
      if (di < NN){
        int d = S_ORD[di];
        float4 pj = *(const float4*)(smem + OFF_H + d*144 + lane8*16);
        float sp = pj.x*wv0 + pj.y*wv1 + pj.z*wv2 + pj.w*wv3;
        sp += __shfl_xor(sp,1); sp += __shfl_xor(sp,2); sp += __shfl_xor(sp,4);
        if (lane8==0) pred[(size_t)t*NN + d] = sp + bb;
      }
    }
  }
}

extern "C" void kernel_launch(void* const* d_in, const int* in_sizes, int n_in,
                              void* d_out, int out_size, void* d_ws, size_t ws_size,
                              hipStream_t stream) {
  const float* x_static=(const float*)d_in[0];
  const float* pf      =(const float*)d_in[1];
  const int*   ei      =(const int*)  d_in[2];
  const float* Ws1=(const float*)d_in[3];
  const float* as1_src=(const float*)d_in[4];
  const float* as1_dst=(const float*)d_in[5];
  const float* bs1=(const float*)d_in[6];
  const float* Ws2=(const float*)d_in[7];
  const float* as2_src=(const float*)d_in[8];
  const float* as2_dst=(const float*)d_in[9];
  const float* bs2=(const float*)d_in[10];
  const float* wd_emb=(const float*)d_in[11];
  const float* sl_emb=(const float*)d_in[12];
  const float* Wc1=(const float*)d_in[13];
  const float* bc1=(const float*)d_in[14];
  const float* Wc2=(const float*)d_in[15];
  const float* bc2=(const float*)d_in[16];
  const float* Wp1=(const float*)d_in[17];
  const float* bp1=(const float*)d_in[18];
  const float* Wp2=(const float*)d_in[19];
  const float* bp2=(const float*)d_in[20];
  const float* Wt1=(const float*)d_in[21];
  const float* at1_src=(const float*)d_in[22];
  const float* at1_dst=(const float*)d_in[23];
  const float* bt1=(const float*)d_in[24];
  const float* Wt2=(const float*)d_in[25];
  const float* at2_src=(const float*)d_in[26];
  const float* at2_dst=(const float*)d_in[27];
  const float* bt2=(const float*)d_in[28];
  const float* Wh1=(const float*)d_in[29];
  const float* bh1=(const float*)d_in[30];
  const float* Wh2=(const float*)d_in[31];
  const float* bh2=(const float*)d_in[32];

  float* Hout=(float*)d_out;
  float* pred=Hout + (size_t)TT*NN*64;

  char* wsp=(char*)d_ws; size_t off=0;
  auto A=[&](size_t n)->void*{ void* p=wsp+off; off=(off+n+255)&~(size_t)255; return p; };
  float* xs    =(float*)A((size_t)NN*32*4);
  float* W_pe  =(float*)A(32*256*4);
  float* b_pe  =(float*)A(256*4);
  float* wpe_s =(float*)A(128*4);
  float* wpe_d =(float*)A(128*4);
  float* wt1_as=(float*)A(128*4);
  float* wt1_ad=(float*)A(128*4);
  float* w2s   =(float*)A(64*4);
  float* w2d   =(float*)A(64*4);
  float* Bpre  =(float*)A((size_t)TT*256*4);
  float* Bal_s =(float*)A((size_t)TT*4*4);
  float* Bal_d =(float*)A((size_t)TT*4*4);
  u32*   xsb   =(u32*)  A((size_t)NN*16*4);
  float* Aal_s =(float*)A((size_t)NN*4*4);
  float* Aal_d =(float*)A((size_t)NN*4*4);
  u16*   Bf1   =(u16*)  A(16384*2);
  u16*   Bf2   =(u16*)  A(4096*2);
  u16*   Bfh   =(u16*)  A(2048*2);
  u16*   rp    =(u16*)  A(404*2);
  u16*   colv  =(u16*)  A(NE*2);
  u16*   ordv  =(u16*)  A(NN*2);

  hipLaunchKernelGGL(k_csr, dim3(1), dim3(1024), 0, stream, ei, rp, colv, ordv);
  hipLaunchKernelGGL(k_prep, dim3(1), dim3(256), 0, stream,
                     Wp2,bp2,Wt1,at1_src,at1_dst,Wt2,at2_src,at2_dst,Wh1,
                     W_pe,b_pe,wpe_s,wpe_d,wt1_as,wt1_ad,w2s,w2d,Bf1,Bf2,Bfh);
  hipLaunchKernelGGL(k_static, dim3(1), dim3(512), 0, stream,
                     x_static,Ws1,as1_src,as1_dst,bs1,Ws2,as2_src,as2_dst,bs2,
                     rp,colv,xs);
  hipLaunchKernelGGL(k_cal, dim3(TT), dim3(256), 0, stream,
                     wd_emb,sl_emb,Wc1,bc1,Wc2,bc2,Wt1,at1_src,at1_dst,b_pe,
                     Bpre,Bal_s,Bal_d);
  hipLaunchKernelGGL(k_xs, dim3(1), dim3(512), 0, stream,
                     xs,wt1_as,wt1_ad,xsb,Aal_s,Aal_d);
  hipLaunchKernelGGL(k_temporal, dim3(TT), dim3(1024), 0, stream,
                     pf,Wp1,bp1,xsb,Aal_s,Aal_d,Bpre,Bal_s,Bal_d,
                     wpe_s,wpe_d,Bf1,Bf2,Bfh,
                     bt1,w2s,w2d,bt2,bh1,Wh2,bh2,
                     rp,colv,ordv,Hout,pred);
}

// Round 4
// 735.660 us; speedup vs baseline: 2.4770x; 1.2484x over previous
//
#include <hip/hip_runtime.h>

typedef unsigned short u16;
typedef unsigned int   u32;
typedef _Float16 f16;
typedef __attribute__((ext_vector_type(8))) _Float16 f16x8;
typedef __attribute__((ext_vector_type(4))) float f32x4;

#define NN  400
#define EIN 3200
#define NE  3600
#define TT  2016

__device__ __forceinline__ u32 pk16(float a, float b){
  auto h = __builtin_amdgcn_cvt_pkrtz(a,b);
  union { decltype(h) v; u32 u; } cv; cv.v = h; return cv.u;
}
__device__ __forceinline__ float hlo(u32 w){
  union { u32 u; __fp16 h[2]; } v; v.u=w; return (float)v.h[0];
}
__device__ __forceinline__ float hhi(u32 w){
  union { u32 u; __fp16 h[2]; } v; v.u=w; return (float)v.h[1];
}

// =============== setup: block0 = CSR, block1 = weight folds + MFMA B-frag packs ===============
__global__ __launch_bounds__(1024) void k_setup(
    const int* __restrict__ ei,
    const float* __restrict__ Wp2, const float* __restrict__ bp2,
    const float* __restrict__ Wt1,
    const float* __restrict__ at1_src, const float* __restrict__ at1_dst,
    const float* __restrict__ Wt2, const float* __restrict__ at2_src, const float* __restrict__ at2_dst,
    const float* __restrict__ Wh1,
    const float* __restrict__ Wc2, const float* __restrict__ bc2,
    u16* __restrict__ rp, u16* __restrict__ col, u16* __restrict__ c144,
    u16* __restrict__ dstA, u16* __restrict__ ord,
    f16* __restrict__ Bf1, f16* __restrict__ Bf2, f16* __restrict__ Bfh,
    float* __restrict__ wpe_s, float* __restrict__ wpe_d,
    float* __restrict__ wt1_as, float* __restrict__ wt1_ad,
    float* __restrict__ w2s, float* __restrict__ w2d,
    float* __restrict__ b_pe2, float* __restrict__ WcW,
    float* __restrict__ wbal_s, float* __restrict__ wbal_d,
    float* __restrict__ balc_s, float* __restrict__ balc_d)
{
  const int tid=threadIdx.x;
  __shared__ int s_src[NE]; __shared__ int s_dst[NE];
  __shared__ int s_deg[NN]; __shared__ int s_rp[NN+1];
  __shared__ float sWpe[8192];
  __shared__ float sWcW[8192];
  __shared__ float sbpe2[256];
  if(blockIdx.x==0){
    for(int e2=tid;e2<NE;e2+=1024){
      s_src[e2]=(e2<EIN)?ei[e2]:(e2-EIN);
      s_dst[e2]=(e2<EIN)?ei[EIN+e2]:(e2-EIN);
    }
    if(tid<NN) s_deg[tid]=0;
    __syncthreads();
    for(int e2=tid;e2<NE;e2+=1024) atomicAdd(&s_deg[s_dst[e2]],1);
    __syncthreads();
    if(tid<=NN){
      int acc=0;
      for(int j=0;j<tid;j++) acc+=s_deg[j];
      s_rp[tid]=acc;
      rp[tid]=(u16)acc;
    }
    if(tid==0){ rp[NN+1]=(u16)NE; rp[NN+2]=(u16)NE; rp[NN+3]=(u16)NE; }
    __syncthreads();
    if(tid<NN){
      int cur=s_rp[tid];
      for(int j=0;j<NE;j++){
        if(s_dst[j]==tid){
          int sv=s_src[j];
          col[cur]=(u16)sv; c144[cur]=(u16)(sv*144); dstA[cur]=(u16)tid;
          cur++;
        }
      }
      int dg=s_deg[tid], rk=0;
      for(int j=0;j<NN;j++) rk += (s_deg[j]>dg)||((s_deg[j]==dg)&&(j<tid));
      ord[rk]=(u16)tid;
    }
  } else {
    for(int i=tid;i<8192;i+=1024){
      int k=i>>8, j=i&255;
      float a=0.f,b=0.f;
      for(int m=0;m<32;m++){
        a+=Wp2[k*32+m]*Wt1[(64+m)*256+j];
        b+=Wc2[k*32+m]*Wt1[(32+m)*256+j];
      }
      sWpe[i]=a; sWcW[i]=b; WcW[i]=b;
    }
    if(tid<256){
      float a=0.f,b=0.f;
      for(int m=0;m<32;m++){ a+=bp2[m]*Wt1[(64+m)*256+tid]; b+=bc2[m]*Wt1[(32+m)*256+tid]; }
      sbpe2[tid]=a+b; b_pe2[tid]=a+b;
    }
    __syncthreads();
    if(tid<128){
      int k=tid>>2,h=tid&3;
      float s=0,d=0,s2=0,d2=0,bs=0,bd=0;
      for(int c=0;c<64;c++){
        float as=at1_src[h*64+c], ad=at1_dst[h*64+c];
        float wv=sWpe[k*256+h*64+c];  s+=wv*as;  d+=wv*ad;
        float w2=Wt1[k*256+h*64+c];   s2+=w2*as; d2+=w2*ad;
        float wc=sWcW[k*256+h*64+c];  bs+=wc*as; bd+=wc*ad;
      }
      wpe_s[tid]=s; wpe_d[tid]=d; wt1_as[tid]=s2; wt1_ad[tid]=d2;
      wbal_s[tid]=bs; wbal_d[tid]=bd;
    }
    if(tid>=128&&tid<192){
      int k=tid-128; float s=0,d=0;
      for(int c=0;c<64;c++){ float wv=Wt2[k*64+c]; s+=wv*at2_src[c]; d+=wv*at2_dst[c]; }
      w2s[k]=s; w2d[k]=d;
    }
    if(tid>=192&&tid<196){
      int h=tid-192; float s=0,d=0;
      for(int c=0;c<64;c++){ float v=sbpe2[h*64+c]; s+=v*at1_src[h*64+c]; d+=v*at1_dst[h*64+c]; }
      balc_s[h]=s; balc_d[h]=d;
    }
    for(int i=tid;i<16384;i+=1024){
      int j=i&7, ll=(i>>3)&63, ks=(i>>9)&1, nt=(i>>10)&3, h=(i>>12)&3;
      int k=ks*32+(ll>>4)*8+j, c=h*64+nt*16+(ll&15);
      float v=(k<32)? sWpe[k*256+c] : Wt1[(k-32)*256+c];
      Bf1[i]=(f16)v;
    }
    for(int i=tid;i<4096;i+=1024){
      int j=i&7, ll=(i>>3)&63, ks=(i>>9)&1, nt=(i>>10)&3;
      Bf2[i]=(f16)Wt2[(ks*32+(ll>>4)*8+j)*64 + nt*16+(ll&15)];
    }
    for(int i=tid;i<2048;i+=1024){
      int j=i&7, ll=(i>>3)&63, ks=(i>>9)&1, nt=(i>>10)&1;
      Bfh[i]=(f16)Wh1[(ks*32+(ll>>4)*8+j)*32 + nt*16+(ll&15)];
    }
  }
}

// =============== static 2-layer GAT (1 block, parallel softmax/agg) ===============
#define SB_W    0
#define SB_X    32768
#define SB_H    45568
#define SB_X1   77568
#define SB_EA   103168
#define SB_ALS  117568
#define SB_ALD  119168
#define SB_COL  120768
#define SB_DST  127968
#define SB_RP   135168
#define SB_AS   135976
#define SB_AD   136104
#define SB_WAS  136232
#define SB_WAD  136744
#define SB_BS   137256
#define SB_END  137384

__global__ __launch_bounds__(1024) void k_static(
    const float* __restrict__ x_static,
    const float* __restrict__ Ws1, const float* __restrict__ as1_src, const float* __restrict__ as1_dst, const float* __restrict__ bs1,
    const float* __restrict__ Ws2, const float* __restrict__ as2_src, const float* __restrict__ as2_dst, const float* __restrict__ bs2,
    const float* __restrict__ wt1_as, const float* __restrict__ wt1_ad,
    const u16* __restrict__ g_rp, const u16* __restrict__ g_col, const u16* __restrict__ g_dst,
    u32* __restrict__ xsb, float* __restrict__ Aal_s, float* __restrict__ Aal_d)
{
  __shared__ __align__(16) char smem[SB_END];
  const int tid=threadIdx.x;
  const int lane8=tid&7, grp=tid>>3;
  float* SW=(float*)(smem+SB_W);
  float* EA=(float*)(smem+SB_EA);
  float* ALS=(float*)(smem+SB_ALS);
  float* ALD=(float*)(smem+SB_ALD);
  const u16* COL=(const u16*)(smem+SB_COL);
  const u16* DST=(const u16*)(smem+SB_DST);
  const u16* RP =(const u16*)(smem+SB_RP);

  for(int i=tid;i<2048;i+=1024) SW[i]=Ws1[i];
  for(int i=tid;i<6400;i+=1024) *(f16*)(smem+SB_X+i*2)=(f16)x_static[i];
  for(int i=tid;i<1800;i+=1024){ ((u32*)(smem+SB_COL))[i]=((const u32*)g_col)[i]; ((u32*)(smem+SB_DST))[i]=((const u32*)g_dst)[i]; }
  if(tid<202) ((u32*)(smem+SB_RP))[tid]=((const u32*)g_rp)[tid];
  if(tid>=256&&tid<288) ((float*)(smem+SB_BS))[tid-256]=bs1[tid-256];
  __syncthreads();

  float racc[4][4];
  #pragma unroll
  for(int m=0;m<4;m++){ racc[m][0]=0.f;racc[m][1]=0.f;racc[m][2]=0.f;racc[m][3]=0.f; }

  for(int h=0;h<4;h++){
    if(tid<32) ((float*)(smem+SB_AS))[tid]=as1_src[h*32+tid];
    else if(tid<64) ((float*)(smem+SB_AD))[tid-32]=as1_dst[h*32+(tid-32)];
    for(int i=tid;i<12800;i+=1024){
      int n=i>>5, cc=i&31;
      const u32* xr=(const u32*)(smem+SB_X+n*32);
      float a=0.f;
      #pragma unroll
      for(int q=0;q<8;q++){ u32 v=xr[q]; a=fmaf(hlo(v),SW[(2*q)*128+h*32+cc],a); a=fmaf(hhi(v),SW[(2*q+1)*128+h*32+cc],a); }
      *(f16*)(smem+SB_H+n*80+cc*2)=(f16)a;
    }
    __syncthreads();
    if(tid<NN){
      const u32* hr=(const u32*)(smem+SB_H+tid*80);
      const float* AS=(const float*)(smem+SB_AS);
      const float* AD=(const float*)(smem+SB_AD);
      float sa=0.f,da=0.f;
      #pragma unroll
      for(int q=0;q<16;q++){
        u32 v=hr[q]; float v0=hlo(v),v1=hhi(v);
        sa=fmaf(v0,AS[2*q],sa); sa=fmaf(v1,AS[2*q+1],sa);
        da=fmaf(v0,AD[2*q],da); da=fmaf(v1,AD[2*q+1],da);
      }
      ALS[tid]=sa; ALD[tid]=da;
    }
    __syncthreads();
    for(int j=tid;j<NE;j+=1024){
      float v=ALS[COL[j]]+ALD[DST[j]];
      v=fmaxf(v,0.2f*v);
      EA[j]=__expf(v);
    }
    __syncthreads();
    #pragma unroll
    for(int m=0;m<4;m++){
      int d=grp+m*128;
      float rt[4]={0.f,0.f,0.f,0.f};
      float inv=0.f;
      if(d<NN){
        int b=RP[d], en=RP[d+1];
        float den=0.f;
        for(int j=b+lane8;j<en;j+=8) den+=EA[j];
        den+=__shfl_xor(den,1); den+=__shfl_xor(den,2); den+=__shfl_xor(den,4);
        inv=__builtin_amdgcn_rcpf(den);
        for(int j=b;j<en;j++){
          float p=EA[j];
          int c80=(int)COL[j]*80;
          uint2 hw=*(const uint2*)(smem+SB_H+c80+lane8*8);
          rt[0]=fmaf(hlo(hw.x),p,rt[0]); rt[1]=fmaf(hhi(hw.x),p,rt[1]);
          rt[2]=fmaf(hlo(hw.y),p,rt[2]); rt[3]=fmaf(hhi(hw.y),p,rt[3]);
        }
      }
      #pragma unroll
      for(int q=0;q<4;q++) racc[m][q]=fmaf(rt[q],inv,racc[m][q]);
    }
    __syncthreads();
  }
  {
    const float* BS=(const float*)(smem+SB_BS);
    #pragma unroll
    for(int m=0;m<4;m++){
      int d=grp+m*128;
      if(d<NN){
        float v0=fmaxf(fmaf(0.25f,racc[m][0],BS[lane8*4+0]),0.f);
        float v1=fmaxf(fmaf(0.25f,racc[m][1],BS[lane8*4+1]),0.f);
        float v2=fmaxf(fmaf(0.25f,racc[m][2],BS[lane8*4+2]),0.f);
        float v3=fmaxf(fmaf(0.25f,racc[m][3],BS[lane8*4+3]),0.f);
        *(uint2*)(smem+SB_X1+d*64+lane8*8)=make_uint2(pk16(v0,v1),pk16(v2,v3));
      }
    }
  }
  __syncthreads();
  // L2 stage
  if(tid<1024) SW[tid]=Ws2[tid];
  if(tid<32){ ((float*)(smem+SB_AS))[tid]=as2_src[tid]; ((float*)(smem+SB_AD))[tid]=as2_dst[tid]; ((float*)(smem+SB_BS))[tid]=bs2[tid]; }
  if(tid>=128&&tid<256){ ((float*)(smem+SB_WAS))[tid-128]=wt1_as[tid-128]; ((float*)(smem+SB_WAD))[tid-128]=wt1_ad[tid-128]; }
  __syncthreads();
  for(int i=tid;i<12800;i+=1024){
    int n=i>>5, cc=i&31;
    const u32* xr=(const u32*)(smem+SB_X1+n*64);
    float a=0.f;
    #pragma unroll
    for(int q=0;q<16;q++){ u32 v=xr[q]; a=fmaf(hlo(v),SW[(2*q)*32+cc],a); a=fmaf(hhi(v),SW[(2*q+1)*32+cc],a); }
    *(f16*)(smem+SB_H+n*80+cc*2)=(f16)a;
  }
  __syncthreads();
  if(tid<NN){
    const u32* hr=(const u32*)(smem+SB_H+tid*80);
    const float* AS=(const float*)(smem+SB_AS);
    const float* AD=(const float*)(smem+SB_AD);
    float sa=0.f,da=0.f;
    #pragma unroll
    for(int q=0;q<16;q++){
      u32 v=hr[q]; float v0=hlo(v),v1=hhi(v);
      sa=fmaf(v0,AS[2*q],sa); sa=fmaf(v1,AS[2*q+1],sa);
      da=fmaf(v0,AD[2*q],da); da=fmaf(v1,AD[2*q+1],da);
    }
    ALS[tid]=sa; ALD[tid]=da;
  }
  __syncthreads();
  for(int j=tid;j<NE;j+=1024){
    float v=ALS[COL[j]]+ALD[DST[j]];
    v=fmaxf(v,0.2f*v);
    EA[j]=__expf(v);
  }
  __syncthreads();
  {
    const float* BS=(const float*)(smem+SB_BS);
    const float* WAS=(const float*)(smem+SB_WAS);
    const float* WAD=(const float*)(smem+SB_WAD);
    #pragma unroll
    for(int m=0;m<4;m++){
      int d=grp+m*128;
      if(d<NN){
        int b=RP[d], en=RP[d+1];
        float den=0.f;
        for(int j=b+lane8;j<en;j+=8) den+=EA[j];
        den+=__shfl_xor(den,1); den+=__shfl_xor(den,2); den+=__shfl_xor(den,4);
        float inv=__builtin_amdgcn_rcpf(den);
        float rt[4]={0.f,0.f,0.f,0.f};
        for(int j=b;j<en;j++){
          float p=EA[j];
          int c80=(int)COL[j]*80;
          uint2 hw=*(const uint2*)(smem+SB_H+c80+lane8*8);
          rt[0]=fmaf(hlo(hw.x),p,rt[0]); rt[1]=fmaf(hhi(hw.x),p,rt[1]);
          rt[2]=fmaf(hlo(hw.y),p,rt[2]); rt[3]=fmaf(hhi(hw.y),p,rt[3]);
        }
        float xq[4];
        #pragma unroll
        for(int q=0;q<4;q++) xq[q]=fmaxf(fmaf(rt[q],inv,BS[lane8*4+q]),0.f);
        float ps[4]={0.f,0.f,0.f,0.f}, pd[4]={0.f,0.f,0.f,0.f};
        #pragma unroll
        for(int q=0;q<4;q++){
          int k=lane8*4+q;
          #pragma unroll
          for(int h2=0;h2<4;h2++){ ps[h2]=fmaf(xq[q],WAS[k*4+h2],ps[h2]); pd[h2]=fmaf(xq[q],WAD[k*4+h2],pd[h2]); }
        }
        #pragma unroll
        for(int h2=0;h2<4;h2++){
          ps[h2]+=__shfl_xor(ps[h2],1); ps[h2]+=__shfl_xor(ps[h2],2); ps[h2]+=__shfl_xor(ps[h2],4);
          pd[h2]+=__shfl_xor(pd[h2],1); pd[h2]+=__shfl_xor(pd[h2],2); pd[h2]+=__shfl_xor(pd[h2],4);
        }
        if(lane8==0){
          #pragma unroll
          for(int h2=0;h2<4;h2++){ Aal_s[d*4+h2]=ps[h2]; Aal_d[d*4+h2]=pd[h2]; }
        }
        xsb[d*16+lane8*2+0]=pk16(xq[0],xq[1]);
        xsb[d*16+lane8*2+1]=pk16(xq[2],xq[3]);
      }
    }
  }
}

// =============== fused temporal (inline calendar, f16 MFMA, dedup softmax) ===============
#define OT_A    0
#define OT_H    57600
#define OT_EA   115200
#define OT_ALS  129600
#define OT_ALD  136000
#define OT_COL  142400
#define OT_C144 149600
#define OT_RP   156800
#define OT_ORD  157608
#define OT_BP   158408
#define OT_WPES 159432
#define OT_WPED 159944
#define OT_W2S  160456
#define OT_W2D  160712
#define OT_BT2  160968
#define OT_BH1  161224
#define OT_WH2  161352
#define OT_BPMT 161480
#define OT_C1   161736
#define OT_FEAT 161864
#define OT_BAL  161992
#define OT_END  162024

__global__ __launch_bounds__(1024) void k_temporal(
    const float* __restrict__ pf, const float* __restrict__ Wp1, const float* __restrict__ bp1,
    const u32* __restrict__ xsb, const float* __restrict__ Aal_s, const float* __restrict__ Aal_d,
    const float* __restrict__ wpe_sg, const float* __restrict__ wpe_dg,
    const f16* __restrict__ Bf1, const f16* __restrict__ Bf2, const f16* __restrict__ Bfh,
    const float* __restrict__ WcW, const float* __restrict__ b_pe2,
    const float* __restrict__ wbal_s, const float* __restrict__ wbal_d,
    const float* __restrict__ balc_s, const float* __restrict__ balc_d,
    const float* __restrict__ Wc1, const float* __restrict__ bc1,
    const float* __restrict__ wd_emb, const float* __restrict__ sl_emb,
    const float* __restrict__ bt1, const float* __restrict__ w2sg, const float* __restrict__ w2dg,
    const float* __restrict__ bt2g, const float* __restrict__ bh1g,
    const float* __restrict__ Wh2g, const float* __restrict__ bh2,
    const u16* __restrict__ g_rp, const u16* __restrict__ g_col,
    const u16* __restrict__ g_c144, const u16* __restrict__ g_ord,
    float* __restrict__ Hout, float* __restrict__ pred)
{
  __shared__ __align__(16) char smem[OT_END];
  const int t=blockIdx.x, tid=threadIdx.x;
  const int l=tid&63, w=tid>>6, lane8=tid&7, grp=tid>>3;
  const int col16=l&15, cr=(l>>4)*4, kbyte=(l>>4)*16;

  float4 pA=make_float4(0,0,0,0), pB=make_float4(0,0,0,0);
  if(tid<NN){ const float4* pp=(const float4*)(pf+((size_t)tid*TT+(size_t)t)*8); pA=pp[0]; pB=pp[1]; }

  // ---- phase 0: staging ----
  for(int i=tid;i<1800;i+=1024) ((u32*)(smem+OT_COL))[i]=((const u32*)g_col)[i];
  for(int i=tid;i<1800;i+=1024) ((u32*)(smem+OT_C144))[i]=((const u32*)g_c144)[i];
  for(int i=tid;i<6400;i+=1024){ int n=i>>4,q=i&15; *(u32*)(smem+OT_A+n*144+64+q*4)=xsb[i]; }
  if(tid<202) ((u32*)(smem+OT_RP))[tid]=((const u32*)g_rp)[tid];
  else if(tid>=256&&tid<456) ((u32*)(smem+OT_ORD))[tid-256]=((const u32*)g_ord)[tid-256];
  else if(tid>=512&&tid<640){ ((float*)(smem+OT_WPES))[tid-512]=wpe_sg[tid-512]; ((float*)(smem+OT_WPED))[tid-512]=wpe_dg[tid-512]; }
  else if(tid>=640&&tid<704){ ((float*)(smem+OT_W2S))[tid-640]=w2sg[tid-640]; ((float*)(smem+OT_W2D))[tid-640]=w2dg[tid-640]; }
  else if(tid>=704&&tid<768){ ((float*)(smem+OT_BT2))[tid-704]=bt2g[tid-704]; }
  else if(tid>=768&&tid<800){ ((float*)(smem+OT_BH1))[tid-768]=bh1g[tid-768]; ((float*)(smem+OT_WH2))[tid-768]=Wh2g[tid-768]; }
  else if(tid>=832&&tid<864){
    int q=tid-832;
    const int wd=t/288, sl=t%288;
    float v=0.f;
    if(q<8) v=wd_emb[wd*8+q];
    else if(q<24) v=sl_emb[sl*16+(q-8)];
    else if(q==24||q==25){ float ta=0.021816615649929116f*(float)sl; v=(q==24)?__sinf(ta):__cosf(ta); }
    else if(q==26||q==27){ float wa=0.8975979010256552f*(float)wd; v=(q==26)?__sinf(wa):__cosf(wa); }
    else if(q==28) v=(wd>=5)?1.f:0.f;
    ((float*)(smem+OT_FEAT))[q]=v;
  }
  __syncthreads();

  // ---- phase 1: c1 (calendar) || P1 + logits ----
  if(tid>=512&&tid<544){
    int q=tid-512;
    float a=bc1[q];
    const float* F=(const float*)(smem+OT_FEAT);
    for(int k=0;k<29;k++) a+=F[k]*Wc1[k*32+q];
    ((float*)(smem+OT_C1))[q]=fmaxf(a,0.f);
  }
  if(tid<NN){
    float px[8]={pA.x,pA.y,pA.z,pA.w,pB.x,pB.y,pB.z,pB.w};
    float pv[32];
    #pragma unroll
    for(int k2=0;k2<32;k2+=2){
      float a0=bp1[k2], a1=bp1[k2+1];
      #pragma unroll
      for(int i2=0;i2<8;i2++){ a0=fmaf(px[i2],Wp1[i2*32+k2],a0); a1=fmaf(px[i2],Wp1[i2*32+k2+1],a1); }
      a0=fmaxf(a0,0.f); a1=fmaxf(a1,0.f);
      pv[k2]=a0; pv[k2+1]=a1;
      *(u32*)(smem+OT_A+tid*144+k2*2)=pk16(a0,a1);
    }
    const float* WS=(const float*)(smem+OT_WPES);
    const float* WD=(const float*)(smem+OT_WPED);
    #pragma unroll
    for(int h=0;h<4;h++){
      float sa=Aal_s[tid*4+h], da=Aal_d[tid*4+h];
      #pragma unroll
      for(int k2=0;k2<32;k2++){ sa=fmaf(pv[k2],WS[k2*4+h],sa); da=fmaf(pv[k2],WD[k2*4+h],da); }
      ((float*)(smem+OT_ALS))[tid*4+h]=sa;
      ((float*)(smem+OT_ALD))[tid*4+h]=da;
    }
  }
  __syncthreads();

  auto mfma_L1=[&](int h){
    f16x8 B0[4],B1[4];
    #pragma unroll
    for(int nt=0;nt<4;nt++){
      B0[nt]=*(const f16x8*)(Bf1+(((h*4+nt)*2+0)*512+l*8));
      B1[nt]=*(const f16x8*)(Bf1+(((h*4+nt)*2+1)*512+l*8));
    }
    for(int mt=w;mt<25;mt+=16){
      const char* arow=smem+OT_A+(mt*16+col16)*144;
      f16x8 a0=*(const f16x8*)(arow+kbyte);
      f16x8 a1=*(const f16x8*)(arow+64+kbyte);
      #pragma unroll
      for(int nt=0;nt<4;nt++){
        f32x4 c={0.f,0.f,0.f,0.f};
        c=__builtin_amdgcn_mfma_f32_16x16x32_f16(a0,B0[nt],c,0,0,0);
        c=__builtin_amdgcn_mfma_f32_16x16x32_f16(a1,B1[nt],c,0,0,0);
        #pragma unroll
        for(int r=0;r<4;r++)
          *(f16*)(smem+OT_H+(mt*16+cr+r)*144+(nt*16+col16)*2)=(f16)c[r];
      }
    }
  };

  // ---- phase 2: MFMA head0 || bpre || Bal ----
  mfma_L1(0);
  if(tid<256){
    float a=b_pe2[tid];
    const float* C1=(const float*)(smem+OT_C1);
    for(int k2=0;k2<32;k2++) a=fmaf(C1[k2],WcW[k2*256+tid],a);
    ((float*)(smem+OT_BP))[tid]=a;
  }
  if(tid>=256&&tid<264){
    int h=tid&3; bool isd=(tid>=260);
    const float* C1=(const float*)(smem+OT_C1);
    const float* wb=isd?wbal_d:wbal_s;
    float a=isd?balc_d[h]:balc_s[h];
    for(int k2=0;k2<32;k2++) a=fmaf(C1[k2],wb[k2*4+h],a);
    ((float*)(smem+OT_BAL))[(isd?4:0)+h]=a;
  }
  __syncthreads();

  const u16* RP  =(const u16*)(smem+OT_RP);
  const u16* ORD =(const u16*)(smem+OT_ORD);
  const u16* COL =(const u16*)(smem+OT_COL);
  const u16* C144=(const u16*)(smem+OT_C144);
  float* EA=(float*)(smem+OT_EA);

  float acc[4][8];
  #pragma unroll
  for(int m=0;m<4;m++){
    #pragma unroll
    for(int q=0;q<8;q++) acc[m][q]=0.f;
  }

  // ---- L1: 4 heads ----
  for(int h=0;h<4;h++){
    if(h==0&&tid<64){
      const float* BP=(const float*)(smem+OT_BP);
      ((float*)(smem+OT_BPMT))[tid]=0.25f*(BP[tid]+BP[64+tid]+BP[128+tid]+BP[192+tid])+bt1[tid];
    }
    const float* ALS=(const float*)(smem+OT_ALS);
    const float* ALD=(const float*)(smem+OT_ALD);
    float bsd=((const float*)(smem+OT_BAL))[h]+((const float*)(smem+OT_BAL))[4+h];
    #pragma unroll
    for(int m=0;m<4;m++){
      int di=grp+m*128;
      float rt[8]={0.f,0.f,0.f,0.f,0.f,0.f,0.f,0.f};
      float inv=0.f;
      if(di<NN){
        int d=ORD[di];
        int b=RP[d], en=RP[d+1];
        float ad=ALD[d*4+h]+bsd;
        float den=0.f;
        for(int j=b+lane8;j<en;j+=8){
          int s=COL[j];
          float v=ALS[s*4+h]+ad;
          v=fmaxf(v,0.2f*v);
          v=__expf(v);
          EA[j]=v; den+=v;
        }
        den+=__shfl_xor(den,1); den+=__shfl_xor(den,2); den+=__shfl_xor(den,4);
        inv=__builtin_amdgcn_rcpf(den);
        const char* HB=smem+OT_H+lane8*16;
        for(int j=b;j<en;j++){
          float p=EA[j];
          int cb=C144[j];
          uint4 hw=*(const uint4*)(HB+cb);
          rt[0]=fmaf(hlo(hw.x),p,rt[0]); rt[1]=fmaf(hhi(hw.x),p,rt[1]);
          rt[2]=fmaf(hlo(hw.y),p,rt[2]); rt[3]=fmaf(hhi(hw.y),p,rt[3]);
          rt[4]=fmaf(hlo(hw.z),p,rt[4]); rt[5]=fmaf(hhi(hw.z),p,rt[5]);
          rt[6]=fmaf(hlo(hw.w),p,rt[6]); rt[7]=fmaf(hhi(hw.w),p,rt[7]);
        }
      }
      #pragma unroll
      for(int q=0;q<8;q++) acc[m][q]=fmaf(rt[q],inv,acc[m][q]);
    }
    __syncthreads();
    if(h<3){ mfma_L1(h+1); __syncthreads(); }
  }

  // ---- g1 = relu(0.25*acc + bpmt) + logits2 + pack ----
  {
    const float* BPMT=(const float*)(smem+OT_BPMT);
    const float* W2S=(const float*)(smem+OT_W2S);
    const float* W2D=(const float*)(smem+OT_W2D);
    #pragma unroll
    for(int m=0;m<4;m++){
      int di=grp+m*128;
      if(di<NN){
        int d=ORD[di];
        float g[8];
        #pragma unroll
        for(int q=0;q<8;q++) g[q]=fmaxf(fmaf(0.25f,acc[m][q],BPMT[lane8*8+q]),0.f);
        float ss=0.f,dd2=0.f;
        #pragma unroll
        for(int q=0;q<8;q++){ ss=fmaf(g[q],W2S[lane8*8+q],ss); dd2=fmaf(g[q],W2D[lane8*8+q],dd2); }
        ss+=__shfl_xor(ss,1); ss+=__shfl_xor(ss,2); ss+=__shfl_xor(ss,4);
        dd2+=__shfl_xor(dd2,1); dd2+=__shfl_xor(dd2,2); dd2+=__shfl_xor(dd2,4);
        if(lane8==0){ ((float*)(smem+OT_ALS))[d]=ss; ((float*)(smem+OT_ALD))[d]=dd2; }
        uint4 pk;
        pk.x=pk16(g[0],g[1]); pk.y=pk16(g[2],g[3]); pk.z=pk16(g[4],g[5]); pk.w=pk16(g[6],g[7]);
        *(uint4*)(smem+OT_A+d*144+lane8*16)=pk;
      }
    }
  }
  __syncthreads();

  // ---- L2 MFMA ----
  {
    f16x8 B0[4],B1[4];
    #pragma unroll
    for(int nt=0;nt<4;nt++){
      B0[nt]=*(const f16x8*)(Bf2+((nt*2+0)*512+l*8));
      B1[nt]=*(const f16x8*)(Bf2+((nt*2+1)*512+l*8));
    }
    for(int mt=w;mt<25;mt+=16){
      const char* arow=smem+OT_A+(mt*16+col16)*144;
      f16x8 a0=*(const f16x8*)(arow+kbyte);
      f16x8 a1=*(const f16x8*)(arow+64+kbyte);
      #pragma unroll
      for(int nt=0;nt<4;nt++){
        f32x4 c={0.f,0.f,0.f,0.f};
        c=__builtin_amdgcn_mfma_f32_16x16x32_f16(a0,B0[nt],c,0,0,0);
        c=__builtin_amdgcn_mfma_f32_16x16x32_f16(a1,B1[nt],c,0,0,0);
        #pragma unroll
        for(int r=0;r<4;r++)
          *(f16*)(smem+OT_H+(mt*16+cr+r)*144+(nt*16+col16)*2)=(f16)c[r];
      }
    }
  }
  __syncthreads();

  // ---- L2 agg -> Hout + pack for MLP ----
  {
    const float* ALS=(const float*)(smem+OT_ALS);
    const float* ALD=(const float*)(smem+OT_ALD);
    const float* BT2=(const float*)(smem+OT_BT2);
    #pragma unroll
    for(int m=0;m<4;m++){
      int di=grp+m*128;
      if(di<NN){
        int d=ORD[di];
        int b=RP[d], en=RP[d+1];
        float ad=ALD[d];
        float den=0.f;
        for(int j=b+lane8;j<en;j+=8){
          int s=COL[j];
          float v=ALS[s]+ad;
          v=fmaxf(v,0.2f*v);
          v=__expf(v);
          EA[j]=v; den+=v;
        }
        den+=__shfl_xor(den,1); den+=__shfl_xor(den,2); den+=__shfl_xor(den,4);
        float inv=__builtin_amdgcn_rcpf(den);
        float rt[8]={0.f,0.f,0.f,0.f,0.f,0.f,0.f,0.f};
        const char* HB=smem+OT_H+lane8*16;
        for(int j=b;j<en;j++){
          float p=EA[j];
          int cb=C144[j];
          uint4 hw=*(const uint4*)(HB+cb);
          rt[0]=fmaf(hlo(hw.x),p,rt[0]); rt[1]=fmaf(hhi(hw.x),p,rt[1]);
          rt[2]=fmaf(hlo(hw.y),p,rt[2]); rt[3]=fmaf(hhi(hw.y),p,rt[3]);
          rt[4]=fmaf(hlo(hw.z),p,rt[4]); rt[5]=fmaf(hhi(hw.z),p,rt[5]);
          rt[6]=fmaf(hlo(hw.w),p,rt[6]); rt[7]=fmaf(hhi(hw.w),p,rt[7]);
        }
        float hv[8];
        #pragma unroll
        for(int q=0;q<8;q++) hv[q]=fmaxf(fmaf(rt[q],inv,BT2[lane8*8+q]),0.f);
        float* hp=Hout+((size_t)t*NN+d)*64+lane8*8;
        *(float4*)(hp)  =make_float4(hv[0],hv[1],hv[2],hv[3]);
        *(float4*)(hp+4)=make_float4(hv[4],hv[5],hv[6],hv[7]);
        uint4 pk;
        pk.x=pk16(hv[0],hv[1]); pk.y=pk16(hv[2],hv[3]); pk.z=pk16(hv[4],hv[5]); pk.w=pk16(hv[6],hv[7]);
        *(uint4*)(smem+OT_A+d*144+lane8*16)=pk;
      }
    }
  }
  __syncthreads();

  // ---- head MLP: pj = relu(H@Wh1+bh1) ----
  {
    f16x8 B0[2],B1[2];
    #pragma unroll
    for(int nt=0;nt<2;nt++){
      B0[nt]=*(const f16x8*)(Bfh+((nt*2+0)*512+l*8));
      B1[nt]=*(const f16x8*)(Bfh+((nt*2+1)*512+l*8));
    }
    for(int mt=w;mt<25;mt+=16){
      const char* arow=smem+OT_A+(mt*16+col16)*144;
      f16x8 a0=*(const f16x8*)(arow+kbyte);
      f16x8 a1=*(const f16x8*)(arow+64+kbyte);
      #pragma unroll
      for(int nt=0;nt<2;nt++){
        float bj=((const float*)(smem+OT_BH1))[nt*16+col16];
        f32x4 c={bj,bj,bj,bj};
        c=__builtin_amdgcn_mfma_f32_16x16x32_f16(a0,B0[nt],c,0,0,0);
        c=__builtin_amdgcn_mfma_f32_16x16x32_f16(a1,B1[nt],c,0,0,0);
        #pragma unroll
        for(int r=0;r<4;r++)
          *(float*)(smem+OT_H+(mt*16+cr+r)*144+(nt*16+col16)*4)=fmaxf(c[r],0.f);
      }
    }
  }
  __syncthreads();

  // ---- pred ----
  {
    const float* WH2=(const float*)(smem+OT_WH2);
    float wv0=WH2[lane8*4+0],wv1=WH2[lane8*4+1],wv2=WH2[lane8*4+2],wv3=WH2[lane8*4+3];
    float bb=bh2[0];
    #pragma unroll
    for(int m=0;m<4;m++){
      int di=grp+m*128;
      if(di<NN){
        int d=ORD[di];
        float4 pj=*(const float4*)(smem+OT_H+d*144+lane8*16);
        float sp=pj.x*wv0+pj.y*wv1+pj.z*wv2+pj.w*wv3;
        sp+=__shfl_xor(sp,1); sp+=__shfl_xor(sp,2); sp+=__shfl_xor(sp,4);
        if(lane8==0) pred[(size_t)t*NN+d]=sp+bb;
      }
    }
  }
}

extern "C" void kernel_launch(void* const* d_in, const int* in_sizes, int n_in,
                              void* d_out, int out_size, void* d_ws, size_t ws_size,
                              hipStream_t stream) {
  const float* x_static=(const float*)d_in[0];
  const float* pf      =(const float*)d_in[1];
  const int*   ei      =(const int*)  d_in[2];
  const float* Ws1=(const float*)d_in[3];
  const float* as1_src=(const float*)d_in[4];
  const float* as1_dst=(const float*)d_in[5];
  const float* bs1=(const float*)d_in[6];
  const float* Ws2=(const float*)d_in[7];
  const float* as2_src=(const float*)d_in[8];
  const float* as2_dst=(const float*)d_in[9];
  const float* bs2=(const float*)d_in[10];
  const float* wd_emb=(const float*)d_in[11];
  const float* sl_emb=(const float*)d_in[12];
  const float* Wc1=(const float*)d_in[13];
  const float* bc1=(const float*)d_in[14];
  const float* Wc2=(const float*)d_in[15];
  const float* bc2=(const float*)d_in[16];
  const float* Wp1=(const float*)d_in[17];
  const float* bp1=(const float*)d_in[18];
  const float* Wp2=(const float*)d_in[19];
  const float* bp2=(const float*)d_in[20];
  const float* Wt1=(const float*)d_in[21];
  const float* at1_src=(const float*)d_in[22];
  const float* at1_dst=(const float*)d_in[23];
  const float* bt1=(const float*)d_in[24];
  const float* Wt2=(const float*)d_in[25];
  const float* at2_src=(const float*)d_in[26];
  const float* at2_dst=(const float*)d_in[27];
  const float* bt2=(const float*)d_in[28];
  const float* Wh1=(const float*)d_in[29];
  const float* bh1=(const float*)d_in[30];
  const float* Wh2=(const float*)d_in[31];
  const float* bh2=(const float*)d_in[32];

  float* Hout=(float*)d_out;
  float* pred=Hout + (size_t)TT*NN*64;

  char* wsp=(char*)d_ws; size_t off=0;
  auto A=[&](size_t n)->void*{ void* p=wsp+off; off=(off+n+255)&~(size_t)255; return p; };
  u16* rp    =(u16*)A(408*2);
  u16* colv  =(u16*)A(NE*2);
  u16* c144  =(u16*)A(NE*2);
  u16* dstA  =(u16*)A(NE*2);
  u16* ordv  =(u16*)A(NN*2);
  f16* Bf1   =(f16*)A(16384*2);
  f16* Bf2   =(f16*)A(4096*2);
  f16* Bfh   =(f16*)A(2048*2);
  float* wpe_s =(float*)A(128*4);
  float* wpe_d =(float*)A(128*4);
  float* wt1_as=(float*)A(128*4);
  float* wt1_ad=(float*)A(128*4);
  float* w2s   =(float*)A(64*4);
  float* w2d   =(float*)A(64*4);
  float* b_pe2 =(float*)A(256*4);
  float* WcW   =(float*)A(8192*4);
  float* wbal_s=(float*)A(128*4);
  float* wbal_d=(float*)A(128*4);
  float* balc_s=(float*)A(4*4);
  float* balc_d=(float*)A(4*4);
  u32*   xsb   =(u32*)A(6400*4);
  float* Aal_s =(float*)A(1600*4);
  float* Aal_d =(float*)A(1600*4);

  hipLaunchKernelGGL(k_setup, dim3(2), dim3(1024), 0, stream,
                     ei, Wp2,bp2,Wt1,at1_src,at1_dst,Wt2,at2_src,at2_dst,Wh1,Wc2,bc2,
                     rp,colv,c144,dstA,ordv,Bf1,Bf2,Bfh,
                     wpe_s,wpe_d,wt1_as,wt1_ad,w2s,w2d,b_pe2,WcW,wbal_s,wbal_d,balc_s,balc_d);
  hipLaunchKernelGGL(k_static, dim3(1), dim3(1024), 0, stream,
                     x_static,Ws1,as1_src,as1_dst,bs1,Ws2,as2_src,as2_dst,bs2,
                     wt1_as,wt1_ad,rp,colv,dstA,xsb,Aal_s,Aal_d);
  hipLaunchKernelGGL(k_temporal, dim3(TT), dim3(1024), 0, stream,
                     pf,Wp1,bp1,xsb,Aal_s,Aal_d,wpe_s,wpe_d,Bf1,Bf2,Bfh,
                     WcW,b_pe2,wbal_s,wbal_d,balc_s,balc_d,
                     Wc1,bc1,wd_emb,sl_emb,bt1,w2s,w2d,bt2,bh1,Wh2,bh2,
                     rp,colv,c144,ordv,Hout,pred);
}

// Round 5
// 697.250 us; speedup vs baseline: 2.6135x; 1.0551x over previous
//
#include <hip/hip_runtime.h>

typedef unsigned short u16;
typedef unsigned int   u32;
typedef _Float16 f16;
typedef __attribute__((ext_vector_type(8))) _Float16 f16x8;
typedef __attribute__((ext_vector_type(4))) float f32x4;

#define NN  400
#define EIN 3200
#define NE  3600
#define TT  2016

__device__ __forceinline__ u32 pk16(float a, float b){
  auto h = __builtin_amdgcn_cvt_pkrtz(a,b);
  union { decltype(h) v; u32 u; } cv; cv.v = h; return cv.u;
}
__device__ __forceinline__ float hlo(u32 w){
  union { u32 u; __fp16 h[2]; } v; v.u=w; return (float)v.h[0];
}
__device__ __forceinline__ float hhi(u32 w){
  union { u32 u; __fp16 h[2]; } v; v.u=w; return (float)v.h[1];
}

// =============== setup: block0 = CSR, block1 = weight folds + MFMA B-frag packs ===============
__global__ __launch_bounds__(1024) void k_setup(
    const int* __restrict__ ei,
    const float* __restrict__ Wp2, const float* __restrict__ bp2,
    const float* __restrict__ Wt1,
    const float* __restrict__ at1_src, const float* __restrict__ at1_dst,
    const float* __restrict__ Wt2, const float* __restrict__ at2_src, const float* __restrict__ at2_dst,
    const float* __restrict__ Wh1,
    const float* __restrict__ Wc2, const float* __restrict__ bc2,
    const float* __restrict__ Ws1, const float* __restrict__ Ws2,
    u16* __restrict__ rp, u16* __restrict__ col, u16* __restrict__ ord,
    f16* __restrict__ Bf1, f16* __restrict__ Bf2, f16* __restrict__ Bfh,
    f16* __restrict__ Bs1, f16* __restrict__ Bs2,
    float* __restrict__ wpe_s, float* __restrict__ wpe_d,
    float* __restrict__ wt1_as, float* __restrict__ wt1_ad,
    float* __restrict__ w2s, float* __restrict__ w2d,
    float* __restrict__ b_pe2, float* __restrict__ WcW,
    float* __restrict__ wbal_s, float* __restrict__ wbal_d,
    float* __restrict__ balc_s, float* __restrict__ balc_d)
{
  const int tid=threadIdx.x;
  __shared__ int s_src[NE]; __shared__ int s_dst[NE];
  __shared__ int s_deg[NN]; __shared__ int s_rp[NN+1];
  __shared__ float sWpe[8192];
  __shared__ float sWcW[8192];
  __shared__ float sbpe2[256];
  if(blockIdx.x==0){
    for(int e2=tid;e2<NE;e2+=1024){
      s_src[e2]=(e2<EIN)?ei[e2]:(e2-EIN);
      s_dst[e2]=(e2<EIN)?ei[EIN+e2]:(e2-EIN);
    }
    if(tid<NN) s_deg[tid]=0;
    __syncthreads();
    for(int e2=tid;e2<NE;e2+=1024) atomicAdd(&s_deg[s_dst[e2]],1);
    __syncthreads();
    if(tid<=NN){
      int acc=0;
      for(int j=0;j<tid;j++) acc+=s_deg[j];
      s_rp[tid]=acc;
      rp[tid]=(u16)acc;
    }
    if(tid==0){ rp[NN+1]=(u16)NE; rp[NN+2]=(u16)NE; rp[NN+3]=(u16)NE; }
    __syncthreads();
    if(tid<NN){
      int cur=s_rp[tid];
      for(int j=0;j<NE;j++){
        if(s_dst[j]==tid){
          col[cur]=(u16)s_src[j];
          cur++;
        }
      }
      int dg=s_deg[tid], rk=0;
      for(int j=0;j<NN;j++) rk += (s_deg[j]>dg)||((s_deg[j]==dg)&&(j<tid));
      ord[rk]=(u16)tid;
    }
  } else {
    for(int i=tid;i<8192;i+=1024){
      int k=i>>8, j=i&255;
      float a=0.f,b=0.f;
      for(int m=0;m<32;m++){
        a+=Wp2[k*32+m]*Wt1[(64+m)*256+j];
        b+=Wc2[k*32+m]*Wt1[(32+m)*256+j];
      }
      sWpe[i]=a; sWcW[i]=b; WcW[i]=b;
    }
    if(tid<256){
      float a=0.f,b=0.f;
      for(int m=0;m<32;m++){ a+=bp2[m]*Wt1[(64+m)*256+tid]; b+=bc2[m]*Wt1[(32+m)*256+tid]; }
      sbpe2[tid]=a+b; b_pe2[tid]=a+b;
    }
    __syncthreads();
    if(tid<128){
      int k=tid>>2,h=tid&3;
      float s=0,d=0,s2=0,d2=0,bs=0,bd=0;
      for(int c=0;c<64;c++){
        float as=at1_src[h*64+c], ad=at1_dst[h*64+c];
        float wv=sWpe[k*256+h*64+c];  s+=wv*as;  d+=wv*ad;
        float w2=Wt1[k*256+h*64+c];   s2+=w2*as; d2+=w2*ad;
        float wc=sWcW[k*256+h*64+c];  bs+=wc*as; bd+=wc*ad;
      }
      wpe_s[tid]=s; wpe_d[tid]=d; wt1_as[tid]=s2; wt1_ad[tid]=d2;
      wbal_s[tid]=bs; wbal_d[tid]=bd;
    }
    if(tid>=128&&tid<192){
      int k=tid-128; float s=0,d=0;
      for(int c=0;c<64;c++){ float wv=Wt2[k*64+c]; s+=wv*at2_src[c]; d+=wv*at2_dst[c]; }
      w2s[k]=s; w2d[k]=d;
    }
    if(tid>=192&&tid<196){
      int h=tid-192; float s=0,d=0;
      for(int c=0;c<64;c++){ float v=sbpe2[h*64+c]; s+=v*at1_src[h*64+c]; d+=v*at1_dst[h*64+c]; }
      balc_s[h]=s; balc_d[h]=d;
    }
    for(int i=tid;i<16384;i+=1024){
      int j=i&7, ll=(i>>3)&63, ks=(i>>9)&1, nt=(i>>10)&3, h=(i>>12)&3;
      int k=ks*32+(ll>>4)*8+j, c=h*64+nt*16+(ll&15);
      float v=(k<32)? sWpe[k*256+c] : Wt1[(k-32)*256+c];
      Bf1[i]=(f16)v;
    }
    for(int i=tid;i<4096;i+=1024){
      int j=i&7, ll=(i>>3)&63, ks=(i>>9)&1, nt=(i>>10)&3;
      Bf2[i]=(f16)Wt2[(ks*32+(ll>>4)*8+j)*64 + nt*16+(ll&15)];
    }
    for(int i=tid;i<2048;i+=1024){
      int j=i&7, ll=(i>>3)&63, ks=(i>>9)&1, nt=(i>>10)&1;
      Bfh[i]=(f16)Wh1[(ks*32+(ll>>4)*8+j)*32 + nt*16+(ll&15)];
    }
    // Bs1: [nt8][64][8], K padded 16->32 (zeros)
    for(int i=tid;i<4096;i+=1024){
      int j=i&7, ll=(i>>3)&63, nt=(i>>9)&7;
      int k=(ll>>4)*8+j, c=nt*16+(ll&15);
      Bs1[i]=(f16)((k<16)? Ws1[k*128+c] : 0.f);
    }
    // Bs2: [nt2][64][8], K=32
    for(int i=tid;i<1024;i+=1024){
      int j=i&7, ll=(i>>3)&63, nt=(i>>9)&1;
      int k=(ll>>4)*8+j, c=nt*16+(ll&15);
      Bs2[i]=(f16)Ws2[k*32+c];
    }
  }
}

// =============== static 2-layer GAT (1 block, MFMA + fused-exp agg) ===============
#define KS_X    0        // f16 [400][40] (80B rows): L1 input K-padded; later x1 [400][32]+pad
#define KS_H    32000    // f16 [400][136] (272B rows): H1 128 cols; later H2 [400][40] (80B)
#define KS_ALS  140800   // f32 [400][4]; later [400]
#define KS_ALD  147200
#define KS_COL  153600   // u16 [3600]
#define KS_RP   160800   // u16 [404]+pad
#define KS_ORD  161608   // u16 [400]
#define KS_AS   162408   // f32 [128]
#define KS_AD   162920   // f32 [128]
#define KS_END  163432

__global__ __launch_bounds__(1024) void k_static(
    const float* __restrict__ x_static,
    const float* __restrict__ as1_src, const float* __restrict__ as1_dst, const float* __restrict__ bs1,
    const float* __restrict__ as2_src, const float* __restrict__ as2_dst, const float* __restrict__ bs2,
    const float* __restrict__ wt1_as, const float* __restrict__ wt1_ad,
    const f16* __restrict__ Bs1, const f16* __restrict__ Bs2,
    const u16* __restrict__ g_rp, const u16* __restrict__ g_col, const u16* __restrict__ g_ord,
    u32* __restrict__ xsb, float* __restrict__ Aal_s, float* __restrict__ Aal_d)
{
  __shared__ __align__(16) char smem[KS_END];
  const int tid=threadIdx.x;
  const int l=tid&63, w=tid>>6;
  const int col16=l&15, cr=(l>>4)*4, kbyte=(l>>4)*16;
  const int lane8=tid&7, grp8=tid>>3;
  const int l16=tid&15, g16=tid>>4, hh=l16>>2, cg=l16&3;
  float* ALS=(float*)(smem+KS_ALS);
  float* ALD=(float*)(smem+KS_ALD);
  const u16* COL=(const u16*)(smem+KS_COL);
  const u16* RP =(const u16*)(smem+KS_RP);
  const u16* ORD=(const u16*)(smem+KS_ORD);
  float* AS=(float*)(smem+KS_AS);
  float* AD=(float*)(smem+KS_AD);

  // stage
  for(int i=tid;i<NN*32;i+=1024){
    int n=i>>5, c=i&31;
    *(f16*)(smem+KS_X+n*80+c*2) = (c<16)? (f16)x_static[n*16+c] : (f16)0.f;
  }
  for(int i=tid;i<1800;i+=1024) ((u32*)(smem+KS_COL))[i]=((const u32*)g_col)[i];
  if(tid<202) ((u32*)(smem+KS_RP))[tid]=((const u32*)g_rp)[tid];
  else if(tid>=256&&tid<456) ((u32*)(smem+KS_ORD))[tid-256]=((const u32*)g_ord)[tid-256];
  else if(tid>=512&&tid<640){ AS[tid-512]=as1_src[tid-512]; AD[tid-512]=as1_dst[tid-512]; }
  __syncthreads();

  // ---- L1 matmul: [400x32pad] @ Bs1 -> H1 [400][128] ----
  {
    f16x8 B[8];
    #pragma unroll
    for(int nt=0;nt<8;nt++) B[nt]=*(const f16x8*)(Bs1+nt*512+l*8);
    for(int mt=w;mt<25;mt+=16){
      f16x8 a=*(const f16x8*)(smem+KS_X+(mt*16+col16)*80+kbyte);
      #pragma unroll
      for(int nt=0;nt<8;nt++){
        f32x4 c={0.f,0.f,0.f,0.f};
        c=__builtin_amdgcn_mfma_f32_16x16x32_f16(a,B[nt],c,0,0,0);
        #pragma unroll
        for(int r=0;r<4;r++)
          *(f16*)(smem+KS_H+(mt*16+cr+r)*272+(nt*16+col16)*2)=(f16)c[r];
      }
    }
  }
  __syncthreads();

  // ---- L1 logits ----
  if(tid<NN){
    #pragma unroll
    for(int h=0;h<4;h++){
      const u32* hr=(const u32*)(smem+KS_H+tid*272+h*64);
      float sa=0.f,da=0.f;
      #pragma unroll
      for(int q=0;q<16;q++){
        u32 v=hr[q]; float v0=hlo(v),v1=hhi(v);
        sa=fmaf(v0,AS[h*32+2*q],sa); sa=fmaf(v1,AS[h*32+2*q+1],sa);
        da=fmaf(v0,AD[h*32+2*q],da); da=fmaf(v1,AD[h*32+2*q+1],da);
      }
      ALS[tid*4+h]=sa; ALD[tid*4+h]=da;
    }
  }
  __syncthreads();

  // ---- L1 agg: 16-lane groups, all 4 heads in one pass ----
  for(int m=0;m<7;m++){
    int di=g16+m*64;
    if(di<NN){
      int d=ORD[di];
      int b=RP[d], en=RP[d+1];
      float ad=ALD[d*4+hh];
      float den=0.f;
      float rt[8]={0.f,0.f,0.f,0.f,0.f,0.f,0.f,0.f};
      for(int j=b;j<en;j++){
        int s=COL[j];
        float v=ALS[s*4+hh]+ad;
        v=fmaxf(v,0.2f*v);
        float p=__expf(v); den+=p;
        uint4 hw=*(const uint4*)(smem+KS_H+s*272+l16*16);
        rt[0]=fmaf(hlo(hw.x),p,rt[0]); rt[1]=fmaf(hhi(hw.x),p,rt[1]);
        rt[2]=fmaf(hlo(hw.y),p,rt[2]); rt[3]=fmaf(hhi(hw.y),p,rt[3]);
        rt[4]=fmaf(hlo(hw.z),p,rt[4]); rt[5]=fmaf(hhi(hw.z),p,rt[5]);
        rt[6]=fmaf(hlo(hw.w),p,rt[6]); rt[7]=fmaf(hhi(hw.w),p,rt[7]);
      }
      float inv=__builtin_amdgcn_rcpf(den);
      float vs[8];
      #pragma unroll
      for(int q=0;q<8;q++){
        float x=rt[q]*inv;
        x+=__shfl_xor(x,4); x+=__shfl_xor(x,8);
        vs[q]=x;
      }
      if(l16<4){
        u32 pk[4];
        #pragma unroll
        for(int q=0;q<4;q++){
          float v0=fmaxf(fmaf(0.25f,vs[2*q],  bs1[cg*8+2*q]),  0.f);
          float v1=fmaxf(fmaf(0.25f,vs[2*q+1],bs1[cg*8+2*q+1]),0.f);
          pk[q]=pk16(v0,v1);
        }
        *(uint4*)(smem+KS_X+d*80+cg*16)=make_uint4(pk[0],pk[1],pk[2],pk[3]);
      }
    }
  }
  __syncthreads();

  // ---- L2 matmul: x1 @ Bs2 -> H2 [400][32] (stride 80) ; restage AS/AD = wt1_as/ad ----
  {
    f16x8 B[2];
    #pragma unroll
    for(int nt=0;nt<2;nt++) B[nt]=*(const f16x8*)(Bs2+nt*512+l*8);
    for(int mt=w;mt<25;mt+=16){
      f16x8 a=*(const f16x8*)(smem+KS_X+(mt*16+col16)*80+kbyte);
      #pragma unroll
      for(int nt=0;nt<2;nt++){
        f32x4 c={0.f,0.f,0.f,0.f};
        c=__builtin_amdgcn_mfma_f32_16x16x32_f16(a,B[nt],c,0,0,0);
        #pragma unroll
        for(int r=0;r<4;r++)
          *(f16*)(smem+KS_H+(mt*16+cr+r)*80+(nt*16+col16)*2)=(f16)c[r];
      }
    }
  }
  if(tid>=512&&tid<640){ AS[tid-512]=wt1_as[tid-512]; AD[tid-512]=wt1_ad[tid-512]; }
  __syncthreads();

  // ---- L2 logits ----
  if(tid<NN){
    const u32* hr=(const u32*)(smem+KS_H+tid*80);
    float sa=0.f,da=0.f;
    #pragma unroll
    for(int q=0;q<16;q++){
      u32 v=hr[q]; float v0=hlo(v),v1=hhi(v);
      sa=fmaf(v0,as2_src[2*q],sa); sa=fmaf(v1,as2_src[2*q+1],sa);
      da=fmaf(v0,as2_dst[2*q],da); da=fmaf(v1,as2_dst[2*q+1],da);
    }
    ALS[tid]=sa; ALD[tid]=da;
  }
  __syncthreads();

  // ---- L2 agg + epilogue (xs, Aal fold, pack) ----
  #pragma unroll
  for(int m=0;m<4;m++){
    int di=grp8+m*128;
    if(di<NN){
      int d=ORD[di];
      int b=RP[d], en=RP[d+1];
      float ad=ALD[d];
      float den=0.f;
      float rt[4]={0.f,0.f,0.f,0.f};
      for(int j=b;j<en;j++){
        int s=COL[j];
        float v=ALS[s]+ad;
        v=fmaxf(v,0.2f*v);
        float p=__expf(v); den+=p;
        uint2 hw=*(const uint2*)(smem+KS_H+s*80+lane8*8);
        rt[0]=fmaf(hlo(hw.x),p,rt[0]); rt[1]=fmaf(hhi(hw.x),p,rt[1]);
        rt[2]=fmaf(hlo(hw.y),p,rt[2]); rt[3]=fmaf(hhi(hw.y),p,rt[3]);
      }
      float inv=__builtin_amdgcn_rcpf(den);
      float xq[4];
      #pragma unroll
      for(int q=0;q<4;q++) xq[q]=fmaxf(fmaf(rt[q],inv,bs2[lane8*4+q]),0.f);
      float ps[4]={0.f,0.f,0.f,0.f}, pd[4]={0.f,0.f,0.f,0.f};
      #pragma unroll
      for(int q=0;q<4;q++){
        int k=lane8*4+q;
        #pragma unroll
        for(int h2=0;h2<4;h2++){ ps[h2]=fmaf(xq[q],AS[k*4+h2],ps[h2]); pd[h2]=fmaf(xq[q],AD[k*4+h2],pd[h2]); }
      }
      #pragma unroll
      for(int h2=0;h2<4;h2++){
        ps[h2]+=__shfl_xor(ps[h2],1); ps[h2]+=__shfl_xor(ps[h2],2); ps[h2]+=__shfl_xor(ps[h2],4);
        pd[h2]+=__shfl_xor(pd[h2],1); pd[h2]+=__shfl_xor(pd[h2],2); pd[h2]+=__shfl_xor(pd[h2],4);
      }
      if(lane8==0){
        #pragma unroll
        for(int h2=0;h2<4;h2++){ Aal_s[d*4+h2]=ps[h2]; Aal_d[d*4+h2]=pd[h2]; }
      }
      xsb[d*16+lane8*2+0]=pk16(xq[0],xq[1]);
      xsb[d*16+lane8*2+1]=pk16(xq[2],xq[3]);
    }
  }
}

// =============== fused temporal (fused-exp agg, no EA/C144) ===============
#define OT_A    0
#define OT_H    57600
#define OT_ALS  115200
#define OT_ALD  121600
#define OT_COL  128000
#define OT_RP   135200
#define OT_ORD  136016
#define OT_BP   136816
#define OT_WPES 137840
#define OT_WPED 138352
#define OT_W2S  138864
#define OT_W2D  139120
#define OT_BT2  139376
#define OT_BH1  139632
#define OT_WH2  139760
#define OT_BPMT 139888
#define OT_C1   140144
#define OT_FEAT 140272
#define OT_BAL  140400
#define OT_END  140432

__global__ __launch_bounds__(1024) void k_temporal(
    const float* __restrict__ pf, const float* __restrict__ Wp1, const float* __restrict__ bp1,
    const u32* __restrict__ xsb, const float* __restrict__ Aal_s, const float* __restrict__ Aal_d,
    const float* __restrict__ wpe_sg, const float* __restrict__ wpe_dg,
    const f16* __restrict__ Bf1, const f16* __restrict__ Bf2, const f16* __restrict__ Bfh,
    const float* __restrict__ WcW, const float* __restrict__ b_pe2,
    const float* __restrict__ wbal_s, const float* __restrict__ wbal_d,
    const float* __restrict__ balc_s, const float* __restrict__ balc_d,
    const float* __restrict__ Wc1, const float* __restrict__ bc1,
    const float* __restrict__ wd_emb, const float* __restrict__ sl_emb,
    const float* __restrict__ bt1, const float* __restrict__ w2sg, const float* __restrict__ w2dg,
    const float* __restrict__ bt2g, const float* __restrict__ bh1g,
    const float* __restrict__ Wh2g, const float* __restrict__ bh2,
    const u16* __restrict__ g_rp, const u16* __restrict__ g_col, const u16* __restrict__ g_ord,
    float* __restrict__ Hout, float* __restrict__ pred)
{
  __shared__ __align__(16) char smem[OT_END];
  const int t=blockIdx.x, tid=threadIdx.x;
  const int l=tid&63, w=tid>>6, lane8=tid&7, grp=tid>>3;
  const int col16=l&15, cr=(l>>4)*4, kbyte=(l>>4)*16;

  float4 pA=make_float4(0,0,0,0), pB=make_float4(0,0,0,0);
  if(tid<NN){ const float4* pp=(const float4*)(pf+((size_t)tid*TT+(size_t)t)*8); pA=pp[0]; pB=pp[1]; }

  // ---- phase 0: staging ----
  for(int i=tid;i<1800;i+=1024) ((u32*)(smem+OT_COL))[i]=((const u32*)g_col)[i];
  for(int i=tid;i<6400;i+=1024){ int n=i>>4,q=i&15; *(u32*)(smem+OT_A+n*144+64+q*4)=xsb[i]; }
  if(tid<202) ((u32*)(smem+OT_RP))[tid]=((const u32*)g_rp)[tid];
  else if(tid>=256&&tid<456) ((u32*)(smem+OT_ORD))[tid-256]=((const u32*)g_ord)[tid-256];
  else if(tid>=512&&tid<640){ ((float*)(smem+OT_WPES))[tid-512]=wpe_sg[tid-512]; ((float*)(smem+OT_WPED))[tid-512]=wpe_dg[tid-512]; }
  else if(tid>=640&&tid<704){ ((float*)(smem+OT_W2S))[tid-640]=w2sg[tid-640]; ((float*)(smem+OT_W2D))[tid-640]=w2dg[tid-640]; }
  else if(tid>=704&&tid<768){ ((float*)(smem+OT_BT2))[tid-704]=bt2g[tid-704]; }
  else if(tid>=768&&tid<800){ ((float*)(smem+OT_BH1))[tid-768]=bh1g[tid-768]; ((float*)(smem+OT_WH2))[tid-768]=Wh2g[tid-768]; }
  else if(tid>=832&&tid<864){
    int q=tid-832;
    const int wd=t/288, sl=t%288;
    float v=0.f;
    if(q<8) v=wd_emb[wd*8+q];
    else if(q<24) v=sl_emb[sl*16+(q-8)];
    else if(q==24||q==25){ float ta=0.021816615649929116f*(float)sl; v=(q==24)?__sinf(ta):__cosf(ta); }
    else if(q==26||q==27){ float wa=0.8975979010256552f*(float)wd; v=(q==26)?__sinf(wa):__cosf(wa); }
    else if(q==28) v=(wd>=5)?1.f:0.f;
    ((float*)(smem+OT_FEAT))[q]=v;
  }
  __syncthreads();

  // ---- phase 1: c1 (calendar) || P1 + logits ----
  if(tid>=512&&tid<544){
    int q=tid-512;
    float a=bc1[q];
    const float* F=(const float*)(smem+OT_FEAT);
    for(int k=0;k<29;k++) a+=F[k]*Wc1[k*32+q];
    ((float*)(smem+OT_C1))[q]=fmaxf(a,0.f);
  }
  if(tid<NN){
    float px[8]={pA.x,pA.y,pA.z,pA.w,pB.x,pB.y,pB.z,pB.w};
    float pv[32];
    #pragma unroll
    for(int k2=0;k2<32;k2+=2){
      float a0=bp1[k2], a1=bp1[k2+1];
      #pragma unroll
      for(int i2=0;i2<8;i2++){ a0=fmaf(px[i2],Wp1[i2*32+k2],a0); a1=fmaf(px[i2],Wp1[i2*32+k2+1],a1); }
      a0=fmaxf(a0,0.f); a1=fmaxf(a1,0.f);
      pv[k2]=a0; pv[k2+1]=a1;
      *(u32*)(smem+OT_A+tid*144+k2*2)=pk16(a0,a1);
    }
    const float* WS=(const float*)(smem+OT_WPES);
    const float* WD=(const float*)(smem+OT_WPED);
    #pragma unroll
    for(int h=0;h<4;h++){
      float sa=Aal_s[tid*4+h], da=Aal_d[tid*4+h];
      #pragma unroll
      for(int k2=0;k2<32;k2++){ sa=fmaf(pv[k2],WS[k2*4+h],sa); da=fmaf(pv[k2],WD[k2*4+h],da); }
      ((float*)(smem+OT_ALS))[tid*4+h]=sa;
      ((float*)(smem+OT_ALD))[tid*4+h]=da;
    }
  }
  __syncthreads();

  auto mfma_L1=[&](int h){
    f16x8 B0[4],B1[4];
    #pragma unroll
    for(int nt=0;nt<4;nt++){
      B0[nt]=*(const f16x8*)(Bf1+(((h*4+nt)*2+0)*512+l*8));
      B1[nt]=*(const f16x8*)(Bf1+(((h*4+nt)*2+1)*512+l*8));
    }
    for(int mt=w;mt<25;mt+=16){
      const char* arow=smem+OT_A+(mt*16+col16)*144;
      f16x8 a0=*(const f16x8*)(arow+kbyte);
      f16x8 a1=*(const f16x8*)(arow+64+kbyte);
      #pragma unroll
      for(int nt=0;nt<4;nt++){
        f32x4 c={0.f,0.f,0.f,0.f};
        c=__builtin_amdgcn_mfma_f32_16x16x32_f16(a0,B0[nt],c,0,0,0);
        c=__builtin_amdgcn_mfma_f32_16x16x32_f16(a1,B1[nt],c,0,0,0);
        #pragma unroll
        for(int r=0;r<4;r++)
          *(f16*)(smem+OT_H+(mt*16+cr+r)*144+(nt*16+col16)*2)=(f16)c[r];
      }
    }
  };

  // ---- phase 2: MFMA head0 || bpre || Bal ----
  mfma_L1(0);
  if(tid<256){
    float a=b_pe2[tid];
    const float* C1=(const float*)(smem+OT_C1);
    for(int k2=0;k2<32;k2++) a=fmaf(C1[k2],WcW[k2*256+tid],a);
    ((float*)(smem+OT_BP))[tid]=a;
  }
  if(tid>=256&&tid<264){
    int h=tid&3; bool isd=(tid>=260);
    const float* C1=(const float*)(smem+OT_C1);
    const float* wb=isd?wbal_d:wbal_s;
    float a=isd?balc_d[h]:balc_s[h];
    for(int k2=0;k2<32;k2++) a=fmaf(C1[k2],wb[k2*4+h],a);
    ((float*)(smem+OT_BAL))[(isd?4:0)+h]=a;
  }
  __syncthreads();

  const u16* RP  =(const u16*)(smem+OT_RP);
  const u16* ORD =(const u16*)(smem+OT_ORD);
  const u16* COL =(const u16*)(smem+OT_COL);

  float acc[4][8];
  #pragma unroll
  for(int m=0;m<4;m++){
    #pragma unroll
    for(int q=0;q<8;q++) acc[m][q]=0.f;
  }

  // ---- L1: 4 heads, fused softmax+gather ----
  for(int h=0;h<4;h++){
    if(h==0&&tid<64){
      const float* BP=(const float*)(smem+OT_BP);
      ((float*)(smem+OT_BPMT))[tid]=0.25f*(BP[tid]+BP[64+tid]+BP[128+tid]+BP[192+tid])+bt1[tid];
    }
    const float* ALS=(const float*)(smem+OT_ALS);
    const float* ALD=(const float*)(smem+OT_ALD);
    float bsd=((const float*)(smem+OT_BAL))[h]+((const float*)(smem+OT_BAL))[4+h];
    #pragma unroll
    for(int m=0;m<4;m++){
      int di=grp+m*128;
      float rt[8]={0.f,0.f,0.f,0.f,0.f,0.f,0.f,0.f};
      float inv=0.f;
      if(di<NN){
        int d=ORD[di];
        int b=RP[d], en=RP[d+1];
        float ad=ALD[d*4+h]+bsd;
        float den=0.f;
        const char* HB=smem+OT_H+lane8*16;
        for(int j=b;j<en;j++){
          int s=COL[j];
          float v=ALS[s*4+h]+ad;
          v=fmaxf(v,0.2f*v);
          float p=__expf(v); den+=p;
          uint4 hw=*(const uint4*)(HB+s*144);
          rt[0]=fmaf(hlo(hw.x),p,rt[0]); rt[1]=fmaf(hhi(hw.x),p,rt[1]);
          rt[2]=fmaf(hlo(hw.y),p,rt[2]); rt[3]=fmaf(hhi(hw.y),p,rt[3]);
          rt[4]=fmaf(hlo(hw.z),p,rt[4]); rt[5]=fmaf(hhi(hw.z),p,rt[5]);
          rt[6]=fmaf(hlo(hw.w),p,rt[6]); rt[7]=fmaf(hhi(hw.w),p,rt[7]);
        }
        inv=__builtin_amdgcn_rcpf(den);
      }
      #pragma unroll
      for(int q=0;q<8;q++) acc[m][q]=fmaf(rt[q],inv,acc[m][q]);
    }
    __syncthreads();
    if(h<3){ mfma_L1(h+1); __syncthreads(); }
  }

  // ---- g1 = relu(0.25*acc + bpmt) + logits2 + pack ----
  {
    const float* BPMT=(const float*)(smem+OT_BPMT);
    const float* W2S=(const float*)(smem+OT_W2S);
    const float* W2D=(const float*)(smem+OT_W2D);
    #pragma unroll
    for(int m=0;m<4;m++){
      int di=grp+m*128;
      if(di<NN){
        int d=ORD[di];
        float g[8];
        #pragma unroll
        for(int q=0;q<8;q++) g[q]=fmaxf(fmaf(0.25f,acc[m][q],BPMT[lane8*8+q]),0.f);
        float ss=0.f,dd2=0.f;
        #pragma unroll
        for(int q=0;q<8;q++){ ss=fmaf(g[q],W2S[lane8*8+q],ss); dd2=fmaf(g[q],W2D[lane8*8+q],dd2); }
        ss+=__shfl_xor(ss,1); ss+=__shfl_xor(ss,2); ss+=__shfl_xor(ss,4);
        dd2+=__shfl_xor(dd2,1); dd2+=__shfl_xor(dd2,2); dd2+=__shfl_xor(dd2,4);
        if(lane8==0){ ((float*)(smem+OT_ALS))[d]=ss; ((float*)(smem+OT_ALD))[d]=dd2; }
        uint4 pk;
        pk.x=pk16(g[0],g[1]); pk.y=pk16(g[2],g[3]); pk.z=pk16(g[4],g[5]); pk.w=pk16(g[6],g[7]);
        *(uint4*)(smem+OT_A+d*144+lane8*16)=pk;
      }
    }
  }
  __syncthreads();

  // ---- L2 MFMA ----
  {
    f16x8 B0[4],B1[4];
    #pragma unroll
    for(int nt=0;nt<4;nt++){
      B0[nt]=*(const f16x8*)(Bf2+((nt*2+0)*512+l*8));
      B1[nt]=*(const f16x8*)(Bf2+((nt*2+1)*512+l*8));
    }
    for(int mt=w;mt<25;mt+=16){
      const char* arow=smem+OT_A+(mt*16+col16)*144;
      f16x8 a0=*(const f16x8*)(arow+kbyte);
      f16x8 a1=*(const f16x8*)(arow+64+kbyte);
      #pragma unroll
      for(int nt=0;nt<4;nt++){
        f32x4 c={0.f,0.f,0.f,0.f};
        c=__builtin_amdgcn_mfma_f32_16x16x32_f16(a0,B0[nt],c,0,0,0);
        c=__builtin_amdgcn_mfma_f32_16x16x32_f16(a1,B1[nt],c,0,0,0);
        #pragma unroll
        for(int r=0;r<4;r++)
          *(f16*)(smem+OT_H+(mt*16+cr+r)*144+(nt*16+col16)*2)=(f16)c[r];
      }
    }
  }
  __syncthreads();

  // ---- L2 agg (fused) -> Hout + pack for MLP ----
  {
    const float* ALS=(const float*)(smem+OT_ALS);
    const float* ALD=(const float*)(smem+OT_ALD);
    const float* BT2=(const float*)(smem+OT_BT2);
    #pragma unroll
    for(int m=0;m<4;m++){
      int di=grp+m*128;
      if(di<NN){
        int d=ORD[di];
        int b=RP[d], en=RP[d+1];
        float ad=ALD[d];
        float den=0.f;
        float rt[8]={0.f,0.f,0.f,0.f,0.f,0.f,0.f,0.f};
        const char* HB=smem+OT_H+lane8*16;
        for(int j=b;j<en;j++){
          int s=COL[j];
          float v=ALS[s]+ad;
          v=fmaxf(v,0.2f*v);
          float p=__expf(v); den+=p;
          uint4 hw=*(const uint4*)(HB+s*144);
          rt[0]=fmaf(hlo(hw.x),p,rt[0]); rt[1]=fmaf(hhi(hw.x),p,rt[1]);
          rt[2]=fmaf(hlo(hw.y),p,rt[2]); rt[3]=fmaf(hhi(hw.y),p,rt[3]);
          rt[4]=fmaf(hlo(hw.z),p,rt[4]); rt[5]=fmaf(hhi(hw.z),p,rt[5]);
          rt[6]=fmaf(hlo(hw.w),p,rt[6]); rt[7]=fmaf(hhi(hw.w),p,rt[7]);
        }
        float inv=__builtin_amdgcn_rcpf(den);
        float hv[8];
        #pragma unroll
        for(int q=0;q<8;q++) hv[q]=fmaxf(fmaf(rt[q],inv,BT2[lane8*8+q]),0.f);
        float* hp=Hout+((size_t)t*NN+d)*64+lane8*8;
        *(float4*)(hp)  =make_float4(hv[0],hv[1],hv[2],hv[3]);
        *(float4*)(hp+4)=make_float4(hv[4],hv[5],hv[6],hv[7]);
        uint4 pk;
        pk.x=pk16(hv[0],hv[1]); pk.y=pk16(hv[2],hv[3]); pk.z=pk16(hv[4],hv[5]); pk.w=pk16(hv[6],hv[7]);
        *(uint4*)(smem+OT_A+d*144+lane8*16)=pk;
      }
    }
  }
  __syncthreads();

  // ---- head MLP: pj = relu(H@Wh1+bh1) ----
  {
    f16x8 B0[2],B1[2];
    #pragma unroll
    for(int nt=0;nt<2;nt++){
      B0[nt]=*(const f16x8*)(Bfh+((nt*2+0)*512+l*8));
      B1[nt]=*(const f16x8*)(Bfh+((nt*2+1)*512+l*8));
    }
    for(int mt=w;mt<25;mt+=16){
      const char* arow=smem+OT_A+(mt*16+col16)*144;
      f16x8 a0=*(const f16x8*)(arow+kbyte);
      f16x8 a1=*(const f16x8*)(arow+64+kbyte);
      #pragma unroll
      for(int nt=0;nt<2;nt++){
        float bj=((const float*)(smem+OT_BH1))[nt*16+col16];
        f32x4 c={bj,bj,bj,bj};
        c=__builtin_amdgcn_mfma_f32_16x16x32_f16(a0,B0[nt],c,0,0,0);
        c=__builtin_amdgcn_mfma_f32_16x16x32_f16(a1,B1[nt],c,0,0,0);
        #pragma unroll
        for(int r=0;r<4;r++)
          *(float*)(smem+OT_H+(mt*16+cr+r)*144+(nt*16+col16)*4)=fmaxf(c[r],0.f);
      }
    }
  }
  __syncthreads();

  // ---- pred ----
  {
    const float* WH2=(const float*)(smem+OT_WH2);
    float wv0=WH2[lane8*4+0],wv1=WH2[lane8*4+1],wv2=WH2[lane8*4+2],wv3=WH2[lane8*4+3];
    float bb=bh2[0];
    #pragma unroll
    for(int m=0;m<4;m++){
      int di=grp+m*128;
      if(di<NN){
        int d=ORD[di];
        float4 pj=*(const float4*)(smem+OT_H+d*144+lane8*16);
        float sp=pj.x*wv0+pj.y*wv1+pj.z*wv2+pj.w*wv3;
        sp+=__shfl_xor(sp,1); sp+=__shfl_xor(sp,2); sp+=__shfl_xor(sp,4);
        if(lane8==0) pred[(size_t)t*NN+d]=sp+bb;
      }
    }
  }
}

extern "C" void kernel_launch(void* const* d_in, const int* in_sizes, int n_in,
                              void* d_out, int out_size, void* d_ws, size_t ws_size,
                              hipStream_t stream) {
  const float* x_static=(const float*)d_in[0];
  const float* pf      =(const float*)d_in[1];
  const int*   ei      =(const int*)  d_in[2];
  const float* Ws1=(const float*)d_in[3];
  const float* as1_src=(const float*)d_in[4];
  const float* as1_dst=(const float*)d_in[5];
  const float* bs1=(const float*)d_in[6];
  const float* Ws2=(const float*)d_in[7];
  const float* as2_src=(const float*)d_in[8];
  const float* as2_dst=(const float*)d_in[9];
  const float* bs2=(const float*)d_in[10];
  const float* wd_emb=(const float*)d_in[11];
  const float* sl_emb=(const float*)d_in[12];
  const float* Wc1=(const float*)d_in[13];
  const float* bc1=(const float*)d_in[14];
  const float* Wc2=(const float*)d_in[15];
  const float* bc2=(const float*)d_in[16];
  const float* Wp1=(const float*)d_in[17];
  const float* bp1=(const float*)d_in[18];
  const float* Wp2=(const float*)d_in[19];
  const float* bp2=(const float*)d_in[20];
  const float* Wt1=(const float*)d_in[21];
  const float* at1_src=(const float*)d_in[22];
  const float* at1_dst=(const float*)d_in[23];
  const float* bt1=(const float*)d_in[24];
  const float* Wt2=(const float*)d_in[25];
  const float* at2_src=(const float*)d_in[26];
  const float* at2_dst=(const float*)d_in[27];
  const float* bt2=(const float*)d_in[28];
  const float* Wh1=(const float*)d_in[29];
  const float* bh1=(const float*)d_in[30];
  const float* Wh2=(const float*)d_in[31];
  const float* bh2=(const float*)d_in[32];

  float* Hout=(float*)d_out;
  float* pred=Hout + (size_t)TT*NN*64;

  char* wsp=(char*)d_ws; size_t off=0;
  auto A=[&](size_t n)->void*{ void* p=wsp+off; off=(off+n+255)&~(size_t)255; return p; };
  u16* rp    =(u16*)A(408*2);
  u16* colv  =(u16*)A(NE*2);
  u16* ordv  =(u16*)A(NN*2);
  f16* Bf1   =(f16*)A(16384*2);
  f16* Bf2   =(f16*)A(4096*2);
  f16* Bfh   =(f16*)A(2048*2);
  f16* Bs1   =(f16*)A(4096*2);
  f16* Bs2   =(f16*)A(1024*2);
  float* wpe_s =(float*)A(128*4);
  float* wpe_d =(float*)A(128*4);
  float* wt1_as=(float*)A(128*4);
  float* wt1_ad=(float*)A(128*4);
  float* w2s   =(float*)A(64*4);
  float* w2d   =(float*)A(64*4);
  float* b_pe2 =(float*)A(256*4);
  float* WcW   =(float*)A(8192*4);
  float* wbal_s=(float*)A(128*4);
  float* wbal_d=(float*)A(128*4);
  float* balc_s=(float*)A(4*4);
  float* balc_d=(float*)A(4*4);
  u32*   xsb   =(u32*)A(6400*4);
  float* Aal_s =(float*)A(1600*4);
  float* Aal_d =(float*)A(1600*4);

  hipLaunchKernelGGL(k_setup, dim3(2), dim3(1024), 0, stream,
                     ei, Wp2,bp2,Wt1,at1_src,at1_dst,Wt2,at2_src,at2_dst,Wh1,Wc2,bc2,Ws1,Ws2,
                     rp,colv,ordv,Bf1,Bf2,Bfh,Bs1,Bs2,
                     wpe_s,wpe_d,wt1_as,wt1_ad,w2s,w2d,b_pe2,WcW,wbal_s,wbal_d,balc_s,balc_d);
  hipLaunchKernelGGL(k_static, dim3(1), dim3(1024), 0, stream,
                     x_static,as1_src,as1_dst,bs1,as2_src,as2_dst,bs2,
                     wt1_as,wt1_ad,Bs1,Bs2,rp,colv,ordv,xsb,Aal_s,Aal_d);
  hipLaunchKernelGGL(k_temporal, dim3(TT), dim3(1024), 0, stream,
                     pf,Wp1,bp1,xsb,Aal_s,Aal_d,wpe_s,wpe_d,Bf1,Bf2,Bfh,
                     WcW,b_pe2,wbal_s,wbal_d,balc_s,balc_d,
                     Wc1,bc1,wd_emb,sl_emb,bt1,w2s,w2d,bt2,bh1,Wh2,bh2,
                     rp,colv,ordv,Hout,pred);
}